// Round 1
// baseline (475.725 us; speedup 1.0000x reference)
//
#include <hip/hip_runtime.h>
#include <hip/hip_bf16.h>
#include <cstdint>
#include <cstddef>

#define D_MODEL 1024
#define SEQ_N   4096
#define BATCH   2

typedef __attribute__((ext_vector_type(4))) float  floatx4;
typedef __attribute__((ext_vector_type(8))) short  short8;

__device__ __forceinline__ unsigned short f2bf(float f) {
  unsigned u = __float_as_uint(f);
  u += 0x7FFFu + ((u >> 16) & 1u);   // round-to-nearest-even
  return (unsigned short)(u >> 16);
}

// ---------------- K1d table: K(r) = (r+eps)^(-|alpha|) * exp(-r/|lam|) ----------------
__global__ void k1d_kernel(float* __restrict__ K1d,
                           const float* __restrict__ alpha_p,
                           const float* __restrict__ lam_p) {
  int r = blockIdx.x * blockDim.x + threadIdx.x;
  if (r >= SEQ_N) return;
  float a   = fabsf(alpha_p[0]);
  float lam = fabsf(lam_p[0]);
  float rf  = (float)r;
  K1d[r] = powf(rf + 1e-4f, -a) * expf(-rf / lam);
}

// ---------------- K output: K[i,j] = K1d[|i-j|] ----------------
__global__ __launch_bounds__(256) void writeK_kernel(float* __restrict__ Kout,
                                                     const float* __restrict__ K1d) {
  size_t t = (size_t)blockIdx.x * 256 + threadIdx.x;
  size_t f = t * 4;
  int i = (int)(f >> 12);
  int j = (int)(f & 4095);
  floatx4 v;
#pragma unroll
  for (int e = 0; e < 4; ++e) {
    int d = i - (j + e); d = d < 0 ? -d : d;
    v[e] = K1d[d];
  }
  *(floatx4*)(Kout + f) = v;
}

// ---------------- generic gemm_bt: C[m,n] = sum_k A[m,k]*B[n,k] ----------------
// ASRC/BSRC: 0 = bf16 global (global_load_lds), 1 = fp32 global (reg-staged cvt->bf16)
// EPI: 0 = bf16 store + col bias; 1 = bf16 store + row bias;
//      2 = f32 store * (1/32) * K1d[|row-col|]; 3 = plain f32 store
#define BM 128
#define BN 128
#define BK 32

template<int ASRC, int BSRC, int EPI>
__global__ __launch_bounds__(256)
void gemm_bt(const void* __restrict__ Ap_, int lda, long sA,
             const void* __restrict__ Bp_, int ldb, long sB,
             void* __restrict__ Cp_, int ldc, long sC,
             int K, const float* __restrict__ bias,
             const float* __restrict__ K1d)
{
  __shared__ unsigned short As[BM * BK];
  __shared__ unsigned short Bs[BN * BK];
  const int tid  = threadIdx.x;
  const int lane = tid & 63;
  const int wave = tid >> 6;
  const int z    = blockIdx.z;
  const int bm0  = blockIdx.y * BM;
  const int bn0  = blockIdx.x * BN;
  const int wm   = (wave >> 1) * 64;   // wave tile 64x64
  const int wn   = (wave & 1) * 64;

  floatx4 acc[4][4] = {};

  const unsigned short* Agb = (const unsigned short*)Ap_ + (size_t)z * (size_t)sA;
  const float*          Agf = (const float*)Ap_          + (size_t)z * (size_t)sA;
  const unsigned short* Bgb = (const unsigned short*)Bp_ + (size_t)z * (size_t)sB;
  const float*          Bgf = (const float*)Bp_          + (size_t)z * (size_t)sB;

  for (int k0 = 0; k0 < K; k0 += BK) {
    // ---- stage A tile [BM][BK] ----
    if constexpr (ASRC == 0) {
#pragma unroll
      for (int t = 0; t < 2; ++t) {
        int bu = wave * 64 + t * 256;        // wave-uniform base unit
        int u  = bu + lane;                  // unit: row=u>>2, 16B chunk=(u&3)
        const unsigned short* src = Agb + (size_t)(bm0 + (u >> 2)) * lda + k0 + (u & 3) * 8;
        __builtin_amdgcn_global_load_lds((const __attribute__((address_space(1))) void*)src,
                                         (__attribute__((address_space(3))) void*)(As + bu * 8),
                                         16, 0, 0);
      }
    } else {
#pragma unroll
      for (int t = 0; t < 2; ++t) {
        int u = tid + t * 256;
        const float* src = Agf + (size_t)(bm0 + (u >> 2)) * lda + k0 + (u & 3) * 8;
        floatx4 x0 = *(const floatx4*)src;
        floatx4 x1 = *(const floatx4*)(src + 4);
        short8 pk;
        pk[0] = (short)f2bf(x0[0]); pk[1] = (short)f2bf(x0[1]);
        pk[2] = (short)f2bf(x0[2]); pk[3] = (short)f2bf(x0[3]);
        pk[4] = (short)f2bf(x1[0]); pk[5] = (short)f2bf(x1[1]);
        pk[6] = (short)f2bf(x1[2]); pk[7] = (short)f2bf(x1[3]);
        *(short8*)(As + u * 8) = pk;
      }
    }
    // ---- stage B tile [BN][BK] ----
    if constexpr (BSRC == 0) {
#pragma unroll
      for (int t = 0; t < 2; ++t) {
        int bu = wave * 64 + t * 256;
        int u  = bu + lane;
        const unsigned short* src = Bgb + (size_t)(bn0 + (u >> 2)) * ldb + k0 + (u & 3) * 8;
        __builtin_amdgcn_global_load_lds((const __attribute__((address_space(1))) void*)src,
                                         (__attribute__((address_space(3))) void*)(Bs + bu * 8),
                                         16, 0, 0);
      }
    } else {
#pragma unroll
      for (int t = 0; t < 2; ++t) {
        int u = tid + t * 256;
        const float* src = Bgf + (size_t)(bn0 + (u >> 2)) * ldb + k0 + (u & 3) * 8;
        floatx4 x0 = *(const floatx4*)src;
        floatx4 x1 = *(const floatx4*)(src + 4);
        short8 pk;
        pk[0] = (short)f2bf(x0[0]); pk[1] = (short)f2bf(x0[1]);
        pk[2] = (short)f2bf(x0[2]); pk[3] = (short)f2bf(x0[3]);
        pk[4] = (short)f2bf(x1[0]); pk[5] = (short)f2bf(x1[1]);
        pk[6] = (short)f2bf(x1[2]); pk[7] = (short)f2bf(x1[3]);
        *(short8*)(Bs + u * 8) = pk;
      }
    }
    __syncthreads();

    // ---- fragments + 16 MFMA ----
    short8 af[4], bf[4];
#pragma unroll
    for (int i = 0; i < 4; ++i)
      af[i] = *(const short8*)(As + (wm + i * 16 + (lane & 15)) * BK + (lane >> 4) * 8);
#pragma unroll
    for (int j = 0; j < 4; ++j)
      bf[j] = *(const short8*)(Bs + (wn + j * 16 + (lane & 15)) * BK + (lane >> 4) * 8);
#pragma unroll
    for (int i = 0; i < 4; ++i)
#pragma unroll
      for (int j = 0; j < 4; ++j)
        acc[i][j] = __builtin_amdgcn_mfma_f32_16x16x32_bf16(af[i], bf[j], acc[i][j], 0, 0, 0);
    __syncthreads();
  }

  // ---- epilogue: C[row=(lane>>4)*4+r][col=lane&15] per 16x16 fragment ----
  const int col0 = bn0 + wn;
  const int row0 = bm0 + wm;
#pragma unroll
  for (int i = 0; i < 4; ++i) {
#pragma unroll
    for (int j = 0; j < 4; ++j) {
      int col   = col0 + j * 16 + (lane & 15);
      int rbase = row0 + i * 16 + (lane >> 4) * 4;
      if constexpr (EPI == 0) {
        unsigned short* C = (unsigned short*)Cp_ + (size_t)z * (size_t)sC;
        float b = bias[col];
#pragma unroll
        for (int r = 0; r < 4; ++r)
          C[(size_t)(rbase + r) * ldc + col] = f2bf(acc[i][j][r] + b);
      } else if constexpr (EPI == 1) {
        unsigned short* C = (unsigned short*)Cp_ + (size_t)z * (size_t)sC;
#pragma unroll
        for (int r = 0; r < 4; ++r)
          C[(size_t)(rbase + r) * ldc + col] = f2bf(acc[i][j][r] + bias[rbase + r]);
      } else if constexpr (EPI == 2) {
        float* C = (float*)Cp_ + (size_t)z * (size_t)sC;
#pragma unroll
        for (int r = 0; r < 4; ++r) {
          int row = rbase + r;
          int d = row - col; d = d < 0 ? -d : d;
          C[(size_t)row * ldc + col] = acc[i][j][r] * 0.03125f * K1d[d];
        }
      } else {
        float* C = (float*)Cp_ + (size_t)z * (size_t)sC;
#pragma unroll
        for (int r = 0; r < 4; ++r)
          C[(size_t)(rbase + r) * ldc + col] = acc[i][j][r];
      }
    }
  }
}

// ---------------- row softmax in place (row length 4096) ----------------
__global__ __launch_bounds__(256)
void softmax_kernel(float* __restrict__ attn) {
  const int tid = threadIdx.x;
  float* p = attn + (size_t)blockIdx.x * SEQ_N;
  floatx4* p4 = (floatx4*)p;
  floatx4 x[4];
  float m = -3.402823466e+38f;
#pragma unroll
  for (int c = 0; c < 4; ++c) {
    x[c] = p4[tid + c * 256];
    m = fmaxf(m, fmaxf(fmaxf(x[c][0], x[c][1]), fmaxf(x[c][2], x[c][3])));
  }
#pragma unroll
  for (int o = 32; o; o >>= 1) m = fmaxf(m, __shfl_xor(m, o));
  __shared__ float redm[4], reds[4];
  if ((tid & 63) == 0) redm[tid >> 6] = m;
  __syncthreads();
  m = fmaxf(fmaxf(redm[0], redm[1]), fmaxf(redm[2], redm[3]));
  float s = 0.f;
#pragma unroll
  for (int c = 0; c < 4; ++c) {
#pragma unroll
    for (int e = 0; e < 4; ++e) {
      float t = __expf(x[c][e] - m);
      x[c][e] = t;
      s += t;
    }
  }
#pragma unroll
  for (int o = 32; o; o >>= 1) s += __shfl_xor(s, o);
  if ((tid & 63) == 0) reds[tid >> 6] = s;
  __syncthreads();
  s = reds[0] + reds[1] + reds[2] + reds[3];
  float inv = 1.0f / s;
#pragma unroll
  for (int c = 0; c < 4; ++c) {
    floatx4 y;
#pragma unroll
    for (int e = 0; e < 4; ++e) y[e] = x[c][e] * inv;
    p4[tid + c * 256] = y;
  }
}

extern "C" void kernel_launch(void* const* d_in, const int* in_sizes, int n_in,
                              void* d_out, int out_size, void* d_ws, size_t ws_size,
                              hipStream_t stream) {
  const float* x     = (const float*)d_in[0];
  const float* Wq    = (const float*)d_in[1];
  const float* bq    = (const float*)d_in[2];
  const float* Wk    = (const float*)d_in[3];
  const float* bk    = (const float*)d_in[4];
  const float* Wv    = (const float*)d_in[5];
  const float* bv    = (const float*)d_in[6];
  const float* alpha = (const float*)d_in[7];
  const float* lam   = (const float*)d_in[8];

  float* outp  = (float*)d_out;
  float* attnp = outp + (size_t)BATCH * SEQ_N * D_MODEL;                 // 2*4096*1024
  float* Kp    = attnp + (size_t)BATCH * SEQ_N * SEQ_N;                  // 2*4096*4096

  char* ws = (char*)d_ws;
  float* K1d = (float*)ws;                                               // 16 KB
  unsigned short* qb = (unsigned short*)(ws + 16384);                    // [8192,1024] bf16
  unsigned short* kb = qb + (size_t)BATCH * SEQ_N * D_MODEL;             // [8192,1024] bf16
  unsigned short* vT = kb + (size_t)BATCH * SEQ_N * D_MODEL;             // [1024,8192] bf16
  // total ws: 16384 + 3*16 MiB ~= 50.3 MB

  k1d_kernel<<<16, 256, 0, stream>>>(K1d, alpha, lam);
  writeK_kernel<<<(SEQ_N * SEQ_N / 4) / 256, 256, 0, stream>>>(Kp, K1d);

  // q = x @ Wq^T + bq -> bf16 [8192 x 1024]
  gemm_bt<1, 1, 0><<<dim3(D_MODEL / BN, BATCH * SEQ_N / BM, 1), 256, 0, stream>>>(
      x, D_MODEL, 0, Wq, D_MODEL, 0, qb, D_MODEL, 0, D_MODEL, bq, nullptr);
  // k = x @ Wk^T + bk -> bf16 [8192 x 1024]
  gemm_bt<1, 1, 0><<<dim3(D_MODEL / BN, BATCH * SEQ_N / BM, 1), 256, 0, stream>>>(
      x, D_MODEL, 0, Wk, D_MODEL, 0, kb, D_MODEL, 0, D_MODEL, bk, nullptr);
  // vT[e,n] = sum_d Wv[e,d] x[n,d] + bv[e] -> bf16 [1024 x 8192]
  gemm_bt<1, 1, 1><<<dim3(BATCH * SEQ_N / BN, D_MODEL / BM, 1), 256, 0, stream>>>(
      Wv, D_MODEL, 0, x, D_MODEL, 0, vT, BATCH * SEQ_N, 0, D_MODEL, bv, nullptr);
  // logits[b,i,j] = (q_i . k_j)/32 * K1d[|i-j|]  (fp32, into attn region)
  gemm_bt<0, 0, 2><<<dim3(SEQ_N / BN, SEQ_N / BM, BATCH), 256, 0, stream>>>(
      qb, D_MODEL, (long)SEQ_N * D_MODEL, kb, D_MODEL, (long)SEQ_N * D_MODEL,
      attnp, SEQ_N, (long)SEQ_N * SEQ_N, D_MODEL, nullptr, K1d);
  // softmax rows in place
  softmax_kernel<<<BATCH * SEQ_N, 256, 0, stream>>>(attnp);
  // out[b,n,d] = sum_k attn[b,n,k] * vT[d, b*4096 + k]
  gemm_bt<1, 0, 3><<<dim3(D_MODEL / BN, SEQ_N / BM, BATCH), 256, 0, stream>>>(
      attnp, SEQ_N, (long)SEQ_N * SEQ_N, vT, BATCH * SEQ_N, (long)SEQ_N,
      outp, D_MODEL, (long)SEQ_N * D_MODEL, SEQ_N, nullptr, nullptr);
}

// Round 2
// 422.107 us; speedup vs baseline: 1.1270x; 1.1270x over previous
//
#include <hip/hip_runtime.h>
#include <hip/hip_bf16.h>
#include <cstdint>
#include <cstddef>

#define D_MODEL 1024
#define SEQ_N   4096
#define BATCH   2

typedef __attribute__((ext_vector_type(4))) float  floatx4;
typedef __attribute__((ext_vector_type(8))) short  short8;
typedef __attribute__((ext_vector_type(4))) short  short4v;

__device__ __forceinline__ unsigned short f2bf(float f) {
  unsigned u = __float_as_uint(f);
  u += 0x7FFFu + ((u >> 16) & 1u);   // round-to-nearest-even
  return (unsigned short)(u >> 16);
}

// ---------------- fp32 -> bf16 bulk convert (8 elems/thread) ----------------
__global__ __launch_bounds__(256) void cvt_bf16_kernel(const float* __restrict__ src,
                                                       unsigned short* __restrict__ dst,
                                                       int n8) {
  int i = blockIdx.x * 256 + threadIdx.x;
  if (i >= n8) return;
  const floatx4* s4 = (const floatx4*)src;
  floatx4 a = s4[i * 2], b = s4[i * 2 + 1];
  short8 pk;
  pk[0] = (short)f2bf(a[0]); pk[1] = (short)f2bf(a[1]);
  pk[2] = (short)f2bf(a[2]); pk[3] = (short)f2bf(a[3]);
  pk[4] = (short)f2bf(b[0]); pk[5] = (short)f2bf(b[1]);
  pk[6] = (short)f2bf(b[2]); pk[7] = (short)f2bf(b[3]);
  *(short8*)(dst + (size_t)i * 8) = pk;
}

// ---------------- K1d table: K(r) = (r+eps)^(-|alpha|) * exp(-r/|lam|) ----------------
__global__ void k1d_kernel(float* __restrict__ K1d,
                           const float* __restrict__ alpha_p,
                           const float* __restrict__ lam_p) {
  int r = blockIdx.x * blockDim.x + threadIdx.x;
  if (r >= SEQ_N) return;
  float a   = fabsf(alpha_p[0]);
  float lam = fabsf(lam_p[0]);
  float rf  = (float)r;
  K1d[r] = powf(rf + 1e-4f, -a) * expf(-rf / lam);
}

// ---------------- K output: K[i,j] = K1d[|i-j|] ----------------
__global__ __launch_bounds__(256) void writeK_kernel(float* __restrict__ Kout,
                                                     const float* __restrict__ K1d) {
  size_t t = (size_t)blockIdx.x * 256 + threadIdx.x;
  size_t f = t * 4;
  int i = (int)(f >> 12);
  int j = (int)(f & 4095);
  floatx4 v;
#pragma unroll
  for (int e = 0; e < 4; ++e) {
    int d = i - (j + e); d = d < 0 ? -d : d;
    v[e] = K1d[d];
  }
  *(floatx4*)(Kout + f) = v;
}

// ---------------- generic gemm_bt: C[m,n] = sum_k A[m,k]*B[n,k] ----------------
// ASRC/BSRC: 0 = bf16 global (global_load_lds), 1 = fp32 global (reg-staged cvt->bf16)
// EPI: 0 = bf16 store + col bias; 1 = bf16 store + row bias;
//      2 = f32 store * (1/32) * K1d[|row-col|]; 3 = plain f32 store
#define BM 128
#define BN 128
#define BK 32

template<int ASRC, int BSRC, int EPI>
__global__ __launch_bounds__(256)
void gemm_bt(const void* __restrict__ Ap_, int lda, long sA,
             const void* __restrict__ Bp_, int ldb, long sB,
             void* __restrict__ Cp_, int ldc, long sC,
             int K, const float* __restrict__ bias,
             const float* __restrict__ K1d)
{
  __shared__ unsigned short As[BM * BK];
  __shared__ unsigned short Bs[BN * BK];
  const int tid  = threadIdx.x;
  const int lane = tid & 63;
  const int wave = tid >> 6;

  // XCD-chunked bijective swizzle (total % 8 == 0 for every launch here):
  // HW assigns flat block i to XCD i%8; give each XCD a contiguous work chunk.
  int gx = (int)gridDim.x, gy = (int)gridDim.y;
  int total = gx * gy * (int)gridDim.z;
  int flat  = (int)blockIdx.z * gx * gy + (int)blockIdx.y * gx + (int)blockIdx.x;
  int w     = (flat & 7) * (total >> 3) + (flat >> 3);
  int bx = w % gx;
  int t_ = w / gx;
  int by = t_ % gy;
  int z  = t_ / gy;

  const int bm0  = by * BM;
  const int bn0  = bx * BN;
  const int wm   = (wave >> 1) * 64;   // wave tile 64x64
  const int wn   = (wave & 1) * 64;

  floatx4 acc[4][4] = {};

  const unsigned short* Agb = (const unsigned short*)Ap_ + (size_t)z * (size_t)sA;
  const float*          Agf = (const float*)Ap_          + (size_t)z * (size_t)sA;
  const unsigned short* Bgb = (const unsigned short*)Bp_ + (size_t)z * (size_t)sB;
  const float*          Bgf = (const float*)Bp_          + (size_t)z * (size_t)sB;

  for (int k0 = 0; k0 < K; k0 += BK) {
    // ---- stage A tile [BM][BK] ----
    if constexpr (ASRC == 0) {
#pragma unroll
      for (int t = 0; t < 2; ++t) {
        int bu = wave * 64 + t * 256;        // wave-uniform base unit
        int u  = bu + lane;                  // unit: row=u>>2, 16B chunk=(u&3)
        const unsigned short* src = Agb + (size_t)(bm0 + (u >> 2)) * lda + k0 + (u & 3) * 8;
        __builtin_amdgcn_global_load_lds((const __attribute__((address_space(1))) void*)src,
                                         (__attribute__((address_space(3))) void*)(As + bu * 8),
                                         16, 0, 0);
      }
    } else {
#pragma unroll
      for (int t = 0; t < 2; ++t) {
        int u = tid + t * 256;
        const float* src = Agf + (size_t)(bm0 + (u >> 2)) * lda + k0 + (u & 3) * 8;
        floatx4 x0 = *(const floatx4*)src;
        floatx4 x1 = *(const floatx4*)(src + 4);
        short8 pk;
        pk[0] = (short)f2bf(x0[0]); pk[1] = (short)f2bf(x0[1]);
        pk[2] = (short)f2bf(x0[2]); pk[3] = (short)f2bf(x0[3]);
        pk[4] = (short)f2bf(x1[0]); pk[5] = (short)f2bf(x1[1]);
        pk[6] = (short)f2bf(x1[2]); pk[7] = (short)f2bf(x1[3]);
        *(short8*)(As + u * 8) = pk;
      }
    }
    // ---- stage B tile [BN][BK] ----
    if constexpr (BSRC == 0) {
#pragma unroll
      for (int t = 0; t < 2; ++t) {
        int bu = wave * 64 + t * 256;
        int u  = bu + lane;
        const unsigned short* src = Bgb + (size_t)(bn0 + (u >> 2)) * ldb + k0 + (u & 3) * 8;
        __builtin_amdgcn_global_load_lds((const __attribute__((address_space(1))) void*)src,
                                         (__attribute__((address_space(3))) void*)(Bs + bu * 8),
                                         16, 0, 0);
      }
    } else {
#pragma unroll
      for (int t = 0; t < 2; ++t) {
        int u = tid + t * 256;
        const float* src = Bgf + (size_t)(bn0 + (u >> 2)) * ldb + k0 + (u & 3) * 8;
        floatx4 x0 = *(const floatx4*)src;
        floatx4 x1 = *(const floatx4*)(src + 4);
        short8 pk;
        pk[0] = (short)f2bf(x0[0]); pk[1] = (short)f2bf(x0[1]);
        pk[2] = (short)f2bf(x0[2]); pk[3] = (short)f2bf(x0[3]);
        pk[4] = (short)f2bf(x1[0]); pk[5] = (short)f2bf(x1[1]);
        pk[6] = (short)f2bf(x1[2]); pk[7] = (short)f2bf(x1[3]);
        *(short8*)(Bs + u * 8) = pk;
      }
    }
    __syncthreads();

    // ---- fragments + 16 MFMA ----
    short8 af[4], bf[4];
#pragma unroll
    for (int i = 0; i < 4; ++i)
      af[i] = *(const short8*)(As + (wm + i * 16 + (lane & 15)) * BK + (lane >> 4) * 8);
#pragma unroll
    for (int j = 0; j < 4; ++j)
      bf[j] = *(const short8*)(Bs + (wn + j * 16 + (lane & 15)) * BK + (lane >> 4) * 8);
#pragma unroll
    for (int i = 0; i < 4; ++i)
#pragma unroll
      for (int j = 0; j < 4; ++j)
        acc[i][j] = __builtin_amdgcn_mfma_f32_16x16x32_bf16(af[i], bf[j], acc[i][j], 0, 0, 0);
    __syncthreads();
  }

  // ---- epilogue: C[row=(lane>>4)*4+r][col=lane&15] per 16x16 fragment ----
  const int col0 = bn0 + wn;
  const int row0 = bm0 + wm;
#pragma unroll
  for (int i = 0; i < 4; ++i) {
#pragma unroll
    for (int j = 0; j < 4; ++j) {
      int col   = col0 + j * 16 + (lane & 15);
      int rbase = row0 + i * 16 + (lane >> 4) * 4;
      if constexpr (EPI == 0) {
        unsigned short* C = (unsigned short*)Cp_ + (size_t)z * (size_t)sC;
        float b = bias[col];
#pragma unroll
        for (int r = 0; r < 4; ++r)
          C[(size_t)(rbase + r) * ldc + col] = f2bf(acc[i][j][r] + b);
      } else if constexpr (EPI == 1) {
        unsigned short* C = (unsigned short*)Cp_ + (size_t)z * (size_t)sC;
#pragma unroll
        for (int r = 0; r < 4; ++r)
          C[(size_t)(rbase + r) * ldc + col] = f2bf(acc[i][j][r] + bias[rbase + r]);
      } else if constexpr (EPI == 2) {
        float* C = (float*)Cp_ + (size_t)z * (size_t)sC;
#pragma unroll
        for (int r = 0; r < 4; ++r) {
          int row = rbase + r;
          int d = row - col; d = d < 0 ? -d : d;
          C[(size_t)row * ldc + col] = acc[i][j][r] * 0.03125f * K1d[d];
        }
      } else {
        float* C = (float*)Cp_ + (size_t)z * (size_t)sC;
#pragma unroll
        for (int r = 0; r < 4; ++r)
          C[(size_t)(rbase + r) * ldc + col] = acc[i][j][r];
      }
    }
  }
}

// ---------------- row softmax in place (row length 4096), optional bf16 copy ----------------
__global__ __launch_bounds__(256)
void softmax_kernel(float* __restrict__ attn, unsigned short* __restrict__ attnb) {
  const int tid = threadIdx.x;
  float* p = attn + (size_t)blockIdx.x * SEQ_N;
  floatx4* p4 = (floatx4*)p;
  floatx4 x[4];
  float m = -3.402823466e+38f;
#pragma unroll
  for (int c = 0; c < 4; ++c) {
    x[c] = p4[tid + c * 256];
    m = fmaxf(m, fmaxf(fmaxf(x[c][0], x[c][1]), fmaxf(x[c][2], x[c][3])));
  }
#pragma unroll
  for (int o = 32; o; o >>= 1) m = fmaxf(m, __shfl_xor(m, o));
  __shared__ float redm[4], reds[4];
  if ((tid & 63) == 0) redm[tid >> 6] = m;
  __syncthreads();
  m = fmaxf(fmaxf(redm[0], redm[1]), fmaxf(redm[2], redm[3]));
  float s = 0.f;
#pragma unroll
  for (int c = 0; c < 4; ++c) {
#pragma unroll
    for (int e = 0; e < 4; ++e) {
      float t = __expf(x[c][e] - m);
      x[c][e] = t;
      s += t;
    }
  }
#pragma unroll
  for (int o = 32; o; o >>= 1) s += __shfl_xor(s, o);
  if ((tid & 63) == 0) reds[tid >> 6] = s;
  __syncthreads();
  s = reds[0] + reds[1] + reds[2] + reds[3];
  float inv = 1.0f / s;
  unsigned short* pb = attnb ? attnb + (size_t)blockIdx.x * SEQ_N : nullptr;
#pragma unroll
  for (int c = 0; c < 4; ++c) {
    floatx4 y;
#pragma unroll
    for (int e = 0; e < 4; ++e) y[e] = x[c][e] * inv;
    p4[tid + c * 256] = y;
    if (pb) {
      short4v yb;
#pragma unroll
      for (int e = 0; e < 4; ++e) yb[e] = (short)f2bf(y[e]);
      *(short4v*)(pb + (size_t)(tid + c * 256) * 4) = yb;
    }
  }
}

extern "C" void kernel_launch(void* const* d_in, const int* in_sizes, int n_in,
                              void* d_out, int out_size, void* d_ws, size_t ws_size,
                              hipStream_t stream) {
  const float* x     = (const float*)d_in[0];
  const float* Wq    = (const float*)d_in[1];
  const float* bq    = (const float*)d_in[2];
  const float* Wk    = (const float*)d_in[3];
  const float* bk    = (const float*)d_in[4];
  const float* Wv    = (const float*)d_in[5];
  const float* bv    = (const float*)d_in[6];
  const float* alpha = (const float*)d_in[7];
  const float* lam   = (const float*)d_in[8];

  float* outp  = (float*)d_out;
  float* attnp = outp + (size_t)BATCH * SEQ_N * D_MODEL;                 // 2*4096*1024
  float* Kp    = attnp + (size_t)BATCH * SEQ_N * SEQ_N;                  // 2*4096*4096

  char* ws = (char*)d_ws;
  float* K1d = (float*)ws;                                               // 16 KB
  unsigned short* qb = (unsigned short*)(ws + 16384);                    // [8192,1024] bf16
  unsigned short* kb = qb + (size_t)BATCH * SEQ_N * D_MODEL;             // [8192,1024] bf16
  unsigned short* vT = kb + (size_t)BATCH * SEQ_N * D_MODEL;             // [1024,8192] bf16
  unsigned short* xb  = vT + (size_t)D_MODEL * BATCH * SEQ_N;            // [8192,1024] bf16
  unsigned short* wqb = xb + (size_t)BATCH * SEQ_N * D_MODEL;            // [1024,1024] bf16
  unsigned short* wkb = wqb + (size_t)D_MODEL * D_MODEL;
  unsigned short* wvb = wkb + (size_t)D_MODEL * D_MODEL;
  unsigned short* attnb = wvb + (size_t)D_MODEL * D_MODEL;               // [8192,4096] bf16

  size_t need = 16384
              + (size_t)4 * BATCH * SEQ_N * D_MODEL * 2   // qb,kb,vT,xb
              + (size_t)3 * D_MODEL * D_MODEL * 2         // wqb,wkb,wvb
              + (size_t)BATCH * SEQ_N * SEQ_N * 2;        // attnb
  const bool fast = ws_size >= need;

  k1d_kernel<<<16, 256, 0, stream>>>(K1d, alpha, lam);
  writeK_kernel<<<(SEQ_N * SEQ_N / 4) / 256, 256, 0, stream>>>(Kp, K1d);

  if (fast) {
    // pre-convert inputs to bf16 once
    cvt_bf16_kernel<<<(BATCH * SEQ_N * D_MODEL / 8 + 255) / 256, 256, 0, stream>>>(
        x, xb, BATCH * SEQ_N * D_MODEL / 8);
    cvt_bf16_kernel<<<(D_MODEL * D_MODEL / 8 + 255) / 256, 256, 0, stream>>>(
        Wq, wqb, D_MODEL * D_MODEL / 8);
    cvt_bf16_kernel<<<(D_MODEL * D_MODEL / 8 + 255) / 256, 256, 0, stream>>>(
        Wk, wkb, D_MODEL * D_MODEL / 8);
    cvt_bf16_kernel<<<(D_MODEL * D_MODEL / 8 + 255) / 256, 256, 0, stream>>>(
        Wv, wvb, D_MODEL * D_MODEL / 8);

    // q = x @ Wq^T + bq -> bf16 [8192 x 1024]
    gemm_bt<0, 0, 0><<<dim3(D_MODEL / BN, BATCH * SEQ_N / BM, 1), 256, 0, stream>>>(
        xb, D_MODEL, 0, wqb, D_MODEL, 0, qb, D_MODEL, 0, D_MODEL, bq, nullptr);
    gemm_bt<0, 0, 0><<<dim3(D_MODEL / BN, BATCH * SEQ_N / BM, 1), 256, 0, stream>>>(
        xb, D_MODEL, 0, wkb, D_MODEL, 0, kb, D_MODEL, 0, D_MODEL, bk, nullptr);
    // vT[e,n] = sum_d Wv[e,d] x[n,d] + bv[e] -> bf16 [1024 x 8192]
    gemm_bt<0, 0, 1><<<dim3(BATCH * SEQ_N / BN, D_MODEL / BM, 1), 256, 0, stream>>>(
        wvb, D_MODEL, 0, xb, D_MODEL, 0, vT, BATCH * SEQ_N, 0, D_MODEL, bv, nullptr);
    // logits[b,i,j] = (q_i . k_j)/32 * K1d[|i-j|]  (fp32, into attn region)
    gemm_bt<0, 0, 2><<<dim3(SEQ_N / BN, SEQ_N / BM, BATCH), 256, 0, stream>>>(
        qb, D_MODEL, (long)SEQ_N * D_MODEL, kb, D_MODEL, (long)SEQ_N * D_MODEL,
        attnp, SEQ_N, (long)SEQ_N * SEQ_N, D_MODEL, nullptr, K1d);
    // softmax rows in place + bf16 copy
    softmax_kernel<<<BATCH * SEQ_N, 256, 0, stream>>>(attnp, attnb);
    // out[b,n,d] = sum_k attnb[b,n,k] * vT[d, b*4096 + k]   (pure bf16 operands)
    gemm_bt<0, 0, 3><<<dim3(D_MODEL / BN, SEQ_N / BM, BATCH), 256, 0, stream>>>(
        attnb, SEQ_N, (long)SEQ_N * SEQ_N, vT, BATCH * SEQ_N, (long)SEQ_N,
        outp, D_MODEL, (long)SEQ_N * D_MODEL, SEQ_N, nullptr, nullptr);
  } else {
    // fallback: round-1 proven path (fp32 reg-staged operands)
    gemm_bt<1, 1, 0><<<dim3(D_MODEL / BN, BATCH * SEQ_N / BM, 1), 256, 0, stream>>>(
        x, D_MODEL, 0, Wq, D_MODEL, 0, qb, D_MODEL, 0, D_MODEL, bq, nullptr);
    gemm_bt<1, 1, 0><<<dim3(D_MODEL / BN, BATCH * SEQ_N / BM, 1), 256, 0, stream>>>(
        x, D_MODEL, 0, Wk, D_MODEL, 0, kb, D_MODEL, 0, D_MODEL, bk, nullptr);
    gemm_bt<1, 1, 1><<<dim3(BATCH * SEQ_N / BN, D_MODEL / BM, 1), 256, 0, stream>>>(
        Wv, D_MODEL, 0, x, D_MODEL, 0, vT, BATCH * SEQ_N, 0, D_MODEL, bv, nullptr);
    gemm_bt<0, 0, 2><<<dim3(SEQ_N / BN, SEQ_N / BM, BATCH), 256, 0, stream>>>(
        qb, D_MODEL, (long)SEQ_N * D_MODEL, kb, D_MODEL, (long)SEQ_N * D_MODEL,
        attnp, SEQ_N, (long)SEQ_N * SEQ_N, D_MODEL, nullptr, K1d);
    softmax_kernel<<<BATCH * SEQ_N, 256, 0, stream>>>(attnp, nullptr);
    gemm_bt<1, 0, 3><<<dim3(D_MODEL / BN, SEQ_N / BM, BATCH), 256, 0, stream>>>(
        attnp, SEQ_N, (long)SEQ_N * SEQ_N, vT, BATCH * SEQ_N, (long)SEQ_N,
        outp, D_MODEL, (long)SEQ_N * D_MODEL, SEQ_N, nullptr, nullptr);
  }
}

// Round 3
// 220.757 us; speedup vs baseline: 2.1550x; 1.9121x over previous
//
#include <hip/hip_runtime.h>
#include <hip/hip_bf16.h>
#include <cstdint>
#include <cstddef>

#define D_MODEL 1024
#define SEQ_N   4096
#define BATCH   2
#define BAND    384   // 3 x 128 col-blocks around the diagonal

typedef __attribute__((ext_vector_type(4))) float  floatx4;
typedef __attribute__((ext_vector_type(8))) short  short8;

__device__ __forceinline__ unsigned short f2bf(float f) {
  unsigned u = __float_as_uint(f);
  u += 0x7FFFu + ((u >> 16) & 1u);   // round-to-nearest-even
  return (unsigned short)(u >> 16);
}
__device__ __forceinline__ float bf2f(unsigned short u) {
  return __uint_as_float(((unsigned)u) << 16);
}

// ---------------- fp32 -> bf16 bulk convert (8 elems/thread) ----------------
__global__ __launch_bounds__(256) void cvt_bf16_kernel(const float* __restrict__ src,
                                                       unsigned short* __restrict__ dst,
                                                       int n8) {
  int i = blockIdx.x * 256 + threadIdx.x;
  if (i >= n8) return;
  const floatx4* s4 = (const floatx4*)src;
  floatx4 a = s4[i * 2], b = s4[i * 2 + 1];
  short8 pk;
  pk[0] = (short)f2bf(a[0]); pk[1] = (short)f2bf(a[1]);
  pk[2] = (short)f2bf(a[2]); pk[3] = (short)f2bf(a[3]);
  pk[4] = (short)f2bf(b[0]); pk[5] = (short)f2bf(b[1]);
  pk[6] = (short)f2bf(b[2]); pk[7] = (short)f2bf(b[3]);
  *(short8*)(dst + (size_t)i * 8) = pk;
}

// ---------------- K1d table ----------------
__global__ void k1d_kernel(float* __restrict__ K1d,
                           const float* __restrict__ alpha_p,
                           const float* __restrict__ lam_p) {
  int r = blockIdx.x * blockDim.x + threadIdx.x;
  if (r >= SEQ_N) return;
  float a   = fabsf(alpha_p[0]);
  float lam = fabsf(lam_p[0]);
  float rf  = (float)r;
  K1d[r] = powf(rf + 1e-4f, -a) * expf(-rf / lam);
}

// ---------------- K output: K[i,j] = K1d[|i-j|] ----------------
__global__ __launch_bounds__(256) void writeK_kernel(float* __restrict__ Kout,
                                                     const float* __restrict__ K1d) {
  size_t t = (size_t)blockIdx.x * 256 + threadIdx.x;
  size_t f = t * 4;
  int i = (int)(f >> 12);
  int j = (int)(f & 4095);
  floatx4 v;
#pragma unroll
  for (int e = 0; e < 4; ++e) {
    int d = i - (j + e); d = d < 0 ? -d : d;
    v[e] = K1d[d];
  }
  *(floatx4*)(Kout + f) = v;
}

// ---------------- generic gemm_bt: C[m,n] = sum_k A[m,k]*B[n,k] ----------------
#define BM 128
#define BN 128
#define BK 32

template<int ASRC, int BSRC, int EPI>
__global__ __launch_bounds__(256)
void gemm_bt(const void* __restrict__ Ap_, int lda, long sA,
             const void* __restrict__ Bp_, int ldb, long sB,
             void* __restrict__ Cp_, int ldc, long sC,
             int K, const float* __restrict__ bias,
             const float* __restrict__ K1d)
{
  __shared__ unsigned short As[BM * BK];
  __shared__ unsigned short Bs[BN * BK];
  const int tid  = threadIdx.x;
  const int lane = tid & 63;
  const int wave = tid >> 6;

  // XCD-chunked bijective swizzle (total % 8 == 0 for every launch here)
  int gx = (int)gridDim.x, gy = (int)gridDim.y;
  int total = gx * gy * (int)gridDim.z;
  int flat  = (int)blockIdx.z * gx * gy + (int)blockIdx.y * gx + (int)blockIdx.x;
  int w     = (flat & 7) * (total >> 3) + (flat >> 3);
  int bx = w % gx;
  int t_ = w / gx;
  int by = t_ % gy;
  int z  = t_ / gy;

  const int bm0  = by * BM;
  const int bn0  = bx * BN;
  const int wm   = (wave >> 1) * 64;
  const int wn   = (wave & 1) * 64;

  floatx4 acc[4][4] = {};

  const unsigned short* Agb = (const unsigned short*)Ap_ + (size_t)z * (size_t)sA;
  const float*          Agf = (const float*)Ap_          + (size_t)z * (size_t)sA;
  const unsigned short* Bgb = (const unsigned short*)Bp_ + (size_t)z * (size_t)sB;
  const float*          Bgf = (const float*)Bp_          + (size_t)z * (size_t)sB;

  for (int k0 = 0; k0 < K; k0 += BK) {
    if constexpr (ASRC == 0) {
#pragma unroll
      for (int t = 0; t < 2; ++t) {
        int bu = wave * 64 + t * 256;
        int u  = bu + lane;
        const unsigned short* src = Agb + (size_t)(bm0 + (u >> 2)) * lda + k0 + (u & 3) * 8;
        __builtin_amdgcn_global_load_lds((const __attribute__((address_space(1))) void*)src,
                                         (__attribute__((address_space(3))) void*)(As + bu * 8),
                                         16, 0, 0);
      }
    } else {
#pragma unroll
      for (int t = 0; t < 2; ++t) {
        int u = tid + t * 256;
        const float* src = Agf + (size_t)(bm0 + (u >> 2)) * lda + k0 + (u & 3) * 8;
        floatx4 x0 = *(const floatx4*)src;
        floatx4 x1 = *(const floatx4*)(src + 4);
        short8 pk;
        pk[0] = (short)f2bf(x0[0]); pk[1] = (short)f2bf(x0[1]);
        pk[2] = (short)f2bf(x0[2]); pk[3] = (short)f2bf(x0[3]);
        pk[4] = (short)f2bf(x1[0]); pk[5] = (short)f2bf(x1[1]);
        pk[6] = (short)f2bf(x1[2]); pk[7] = (short)f2bf(x1[3]);
        *(short8*)(As + u * 8) = pk;
      }
    }
    if constexpr (BSRC == 0) {
#pragma unroll
      for (int t = 0; t < 2; ++t) {
        int bu = wave * 64 + t * 256;
        int u  = bu + lane;
        const unsigned short* src = Bgb + (size_t)(bn0 + (u >> 2)) * ldb + k0 + (u & 3) * 8;
        __builtin_amdgcn_global_load_lds((const __attribute__((address_space(1))) void*)src,
                                         (__attribute__((address_space(3))) void*)(Bs + bu * 8),
                                         16, 0, 0);
      }
    } else {
#pragma unroll
      for (int t = 0; t < 2; ++t) {
        int u = tid + t * 256;
        const float* src = Bgf + (size_t)(bn0 + (u >> 2)) * ldb + k0 + (u & 3) * 8;
        floatx4 x0 = *(const floatx4*)src;
        floatx4 x1 = *(const floatx4*)(src + 4);
        short8 pk;
        pk[0] = (short)f2bf(x0[0]); pk[1] = (short)f2bf(x0[1]);
        pk[2] = (short)f2bf(x0[2]); pk[3] = (short)f2bf(x0[3]);
        pk[4] = (short)f2bf(x1[0]); pk[5] = (short)f2bf(x1[1]);
        pk[6] = (short)f2bf(x1[2]); pk[7] = (short)f2bf(x1[3]);
        *(short8*)(Bs + u * 8) = pk;
      }
    }
    __syncthreads();

    short8 af[4], bf[4];
#pragma unroll
    for (int i = 0; i < 4; ++i)
      af[i] = *(const short8*)(As + (wm + i * 16 + (lane & 15)) * BK + (lane >> 4) * 8);
#pragma unroll
    for (int j = 0; j < 4; ++j)
      bf[j] = *(const short8*)(Bs + (wn + j * 16 + (lane & 15)) * BK + (lane >> 4) * 8);
#pragma unroll
    for (int i = 0; i < 4; ++i)
#pragma unroll
      for (int j = 0; j < 4; ++j)
        acc[i][j] = __builtin_amdgcn_mfma_f32_16x16x32_bf16(af[i], bf[j], acc[i][j], 0, 0, 0);
    __syncthreads();
  }

  const int col0 = bn0 + wn;
  const int row0 = bm0 + wm;
#pragma unroll
  for (int i = 0; i < 4; ++i) {
#pragma unroll
    for (int j = 0; j < 4; ++j) {
      int col   = col0 + j * 16 + (lane & 15);
      int rbase = row0 + i * 16 + (lane >> 4) * 4;
      if constexpr (EPI == 0) {
        unsigned short* C = (unsigned short*)Cp_ + (size_t)z * (size_t)sC;
        float b = bias[col];
#pragma unroll
        for (int r = 0; r < 4; ++r)
          C[(size_t)(rbase + r) * ldc + col] = f2bf(acc[i][j][r] + b);
      } else if constexpr (EPI == 1) {
        unsigned short* C = (unsigned short*)Cp_ + (size_t)z * (size_t)sC;
#pragma unroll
        for (int r = 0; r < 4; ++r)
          C[(size_t)(rbase + r) * ldc + col] = f2bf(acc[i][j][r] + bias[rbase + r]);
      } else if constexpr (EPI == 2) {
        float* C = (float*)Cp_ + (size_t)z * (size_t)sC;
#pragma unroll
        for (int r = 0; r < 4; ++r) {
          int row = rbase + r;
          int d = row - col; d = d < 0 ? -d : d;
          C[(size_t)row * ldc + col] = acc[i][j][r] * 0.03125f * K1d[d];
        }
      } else {
        float* C = (float*)Cp_ + (size_t)z * (size_t)sC;
#pragma unroll
        for (int r = 0; r < 4; ++r)
          C[(size_t)(rbase + r) * ldc + col] = acc[i][j][r];
      }
    }
  }
}

// ---------------- band logits: Sband[z][i][t] = (q_i.k_c)/32*K1d[|i-c|], c=bi*128-128+t ----------------
__global__ __launch_bounds__(256)
void band_logits(const unsigned short* __restrict__ Q,
                 const unsigned short* __restrict__ Kb,
                 float* __restrict__ Sband,
                 const float* __restrict__ K1d)
{
  __shared__ unsigned short As[128 * 32];
  __shared__ unsigned short Bs[128 * 32];
  const int tid = threadIdx.x, lane = tid & 63, wave = tid >> 6;
  const int bx = blockIdx.x;            // 0..2  (band third)
  const int by = blockIdx.y;            // 0..31 (row block)
  const int z  = blockIdx.z;
  const int bm0 = by * 128;
  const int bn0 = (by + bx - 1) * 128;  // global col base; may be -128 or 4096
  const bool live = (unsigned)bn0 < (unsigned)SEQ_N;   // block-uniform
  const int wm = (wave >> 1) * 64, wn = (wave & 1) * 64;
  floatx4 acc[4][4] = {};

  if (live) {
    const unsigned short* Ag = Q  + (size_t)z * SEQ_N * D_MODEL;
    const unsigned short* Bg = Kb + (size_t)z * SEQ_N * D_MODEL;
    for (int k0 = 0; k0 < D_MODEL; k0 += 32) {
#pragma unroll
      for (int t = 0; t < 2; ++t) {
        int bu = wave * 64 + t * 256;
        int u  = bu + lane;
        const unsigned short* srcA = Ag + (size_t)(bm0 + (u >> 2)) * D_MODEL + k0 + (u & 3) * 8;
        __builtin_amdgcn_global_load_lds((const __attribute__((address_space(1))) void*)srcA,
                                         (__attribute__((address_space(3))) void*)(As + bu * 8), 16, 0, 0);
        const unsigned short* srcB = Bg + (size_t)(bn0 + (u >> 2)) * D_MODEL + k0 + (u & 3) * 8;
        __builtin_amdgcn_global_load_lds((const __attribute__((address_space(1))) void*)srcB,
                                         (__attribute__((address_space(3))) void*)(Bs + bu * 8), 16, 0, 0);
      }
      __syncthreads();
      short8 af[4], bf[4];
#pragma unroll
      for (int i = 0; i < 4; ++i)
        af[i] = *(const short8*)(As + (wm + i * 16 + (lane & 15)) * 32 + (lane >> 4) * 8);
#pragma unroll
      for (int j = 0; j < 4; ++j)
        bf[j] = *(const short8*)(Bs + (wn + j * 16 + (lane & 15)) * 32 + (lane >> 4) * 8);
#pragma unroll
      for (int i = 0; i < 4; ++i)
#pragma unroll
        for (int j = 0; j < 4; ++j)
          acc[i][j] = __builtin_amdgcn_mfma_f32_16x16x32_bf16(af[i], bf[j], acc[i][j], 0, 0, 0);
      __syncthreads();
    }
  }

  float* Cb = Sband + ((size_t)z * SEQ_N + bm0) * BAND + bx * 128;
#pragma unroll
  for (int i = 0; i < 4; ++i) {
#pragma unroll
    for (int j = 0; j < 4; ++j) {
      int cl  = wn + j * 16 + (lane & 15);
      int rl0 = wm + i * 16 + (lane >> 4) * 4;
#pragma unroll
      for (int r = 0; r < 4; ++r) {
        float v = 0.f;
        if (live) {
          int d = (bm0 + rl0 + r) - (bn0 + cl); d = d < 0 ? -d : d;
          v = acc[i][j][r] * 0.03125f * K1d[d];
        }
        Cb[(size_t)(rl0 + r) * BAND + cl] = v;
      }
    }
  }
}

// ---------------- band softmax: full attn row + bf16 (P-c) band + c ----------------
__global__ __launch_bounds__(256)
void softmax_band(const float* __restrict__ Sband,
                  float* __restrict__ attn,
                  unsigned short* __restrict__ Pb,
                  float* __restrict__ c_arr)
{
  __shared__ float lds_e[4][BAND];
  const int lane = threadIdx.x & 63, wave = threadIdx.x >> 6;
  const int gi = blockIdx.x * 4 + wave;     // 0..8191
  const int ii = gi & (SEQ_N - 1);
  const int bi = ii >> 7;
  const int cbase = bi * 128 - 128;
  const float* S = Sband + (size_t)gi * BAND;

  float sv[6];
  float m = 0.0f;                            // far logits are exactly 0
#pragma unroll
  for (int j = 0; j < 6; ++j) {
    int t = j * 64 + lane;
    int col = cbase + t;
    sv[j] = S[t];
    if ((unsigned)col < (unsigned)SEQ_N) m = fmaxf(m, sv[j]);
  }
#pragma unroll
  for (int o = 32; o; o >>= 1) m = fmaxf(m, __shfl_xor(m, o));

  float s = 0.f;
#pragma unroll
  for (int j = 0; j < 6; ++j) {
    int t = j * 64 + lane;
    int col = cbase + t;
    float e = ((unsigned)col < (unsigned)SEQ_N) ? __expf(sv[j] - m) : 0.f;
    sv[j] = e;
    s += e;
  }
#pragma unroll
  for (int o = 32; o; o >>= 1) s += __shfl_xor(s, o);

  int n_valid = BAND - ((bi == 0) ? 128 : 0) - ((bi == 31) ? 128 : 0);
  float efar  = __expf(-m);
  float denom = s + (float)(SEQ_N - n_valid) * efar;
  float inv   = 1.0f / denom;
  float c     = efar * inv;

  unsigned short* prow = Pb + (size_t)gi * BAND;
#pragma unroll
  for (int j = 0; j < 6; ++j) {
    int t = j * 64 + lane;
    float p = sv[j] * inv;                  // 0 for invalid slots
    lds_e[wave][t] = p;
    int col = cbase + t;
    prow[t] = ((unsigned)col < (unsigned)SEQ_N) ? f2bf(p - c) : (unsigned short)0;
  }
  if (lane == 0) c_arr[gi] = c;

  float* arow = attn + (size_t)gi * SEQ_N;
#pragma unroll
  for (int jj = 0; jj < 16; ++jj) {
    int col0 = jj * 256 + lane * 4;
    floatx4 o;
#pragma unroll
    for (int e = 0; e < 4; ++e) {
      int t = col0 + e - cbase;
      o[e] = ((unsigned)t < (unsigned)BAND) ? lds_e[wave][t] : c;
    }
    *(floatx4*)(arow + col0) = o;
  }
}

// ---------------- colsumV[b][d] = sum_n vT[d][b*4096+n] ----------------
__global__ __launch_bounds__(256)
void colsumv_kernel(const unsigned short* __restrict__ vT, float* __restrict__ colsumV) {
  const int lane = threadIdx.x & 63, wave = threadIdx.x >> 6;
  const int idx = blockIdx.x * 4 + wave;     // 0..2047
  const int d = idx >> 1, b = idx & 1;
  const unsigned short* p = vT + (size_t)d * (BATCH * SEQ_N) + b * SEQ_N;
  float s = 0.f;
#pragma unroll
  for (int it = 0; it < 8; ++it) {
    short8 v = *(const short8*)(p + (size_t)(it * 512 + lane * 8));
#pragma unroll
    for (int e = 0; e < 8; ++e) s += bf2f((unsigned short)v[e]);
  }
#pragma unroll
  for (int o = 32; o; o >>= 1) s += __shfl_xor(s, o);
  if (lane == 0) colsumV[b * D_MODEL + d] = s;
}

// ---------------- band PV: out = (P-c) @ V_band + c * colsumV ----------------
__global__ __launch_bounds__(256)
void band_pv(const unsigned short* __restrict__ Pb,   // [2][4096][384]
             const unsigned short* __restrict__ vT,   // [1024][8192]
             const float* __restrict__ c_arr,         // [2][4096]
             const float* __restrict__ colsumV,       // [2][1024]
             float* __restrict__ outp)                // [2][4096][1024]
{
  __shared__ unsigned short As[128 * 32];
  __shared__ unsigned short Bs[128 * 32];
  const int tid = threadIdx.x, lane = tid & 63, wave = tid >> 6;
  const int bx = blockIdx.x;     // 0..7  d-block
  const int by = blockIdx.y;     // 0..31 row-block
  const int z  = blockIdx.z;
  const int bm0 = by * 128;
  const int bn0 = bx * 128;
  const int wm = (wave >> 1) * 64, wn = (wave & 1) * 64;

  const unsigned short* Ag = Pb + ((size_t)z * SEQ_N + bm0) * BAND;
  // B row d, band col t -> vT[d][z*4096 + by*128 - 128 + t]; base may be 128 elems
  // before vT (lands in kb, finite bf16, always multiplied by P==0) and may spill
  // a few elems past (lands in xb) -- deterministic, in-bounds of d_ws.
  const unsigned short* Bg = vT + ((long)z * SEQ_N + (long)by * 128 - 128);

  floatx4 acc[4][4] = {};
  for (int k0 = 0; k0 < BAND; k0 += 32) {
#pragma unroll
    for (int t = 0; t < 2; ++t) {
      int bu = wave * 64 + t * 256;
      int u  = bu + lane;
      const unsigned short* srcA = Ag + (size_t)(u >> 2) * BAND + k0 + (u & 3) * 8;
      __builtin_amdgcn_global_load_lds((const __attribute__((address_space(1))) void*)srcA,
                                       (__attribute__((address_space(3))) void*)(As + bu * 8), 16, 0, 0);
      const unsigned short* srcB = Bg + (size_t)(bn0 + (u >> 2)) * (BATCH * SEQ_N) + k0 + (u & 3) * 8;
      __builtin_amdgcn_global_load_lds((const __attribute__((address_space(1))) void*)srcB,
                                       (__attribute__((address_space(3))) void*)(Bs + bu * 8), 16, 0, 0);
    }
    __syncthreads();
    short8 af[4], bf[4];
#pragma unroll
    for (int i = 0; i < 4; ++i)
      af[i] = *(const short8*)(As + (wm + i * 16 + (lane & 15)) * 32 + (lane >> 4) * 8);
#pragma unroll
    for (int j = 0; j < 4; ++j)
      bf[j] = *(const short8*)(Bs + (wn + j * 16 + (lane & 15)) * 32 + (lane >> 4) * 8);
#pragma unroll
    for (int i = 0; i < 4; ++i)
#pragma unroll
      for (int j = 0; j < 4; ++j)
        acc[i][j] = __builtin_amdgcn_mfma_f32_16x16x32_bf16(af[i], bf[j], acc[i][j], 0, 0, 0);
    __syncthreads();
  }

#pragma unroll
  for (int i = 0; i < 4; ++i) {
#pragma unroll
    for (int j = 0; j < 4; ++j) {
      int col   = bn0 + wn + j * 16 + (lane & 15);
      int rbase = bm0 + wm + i * 16 + (lane >> 4) * 4;
      float csv = colsumV[z * D_MODEL + col];
#pragma unroll
      for (int r = 0; r < 4; ++r) {
        int row = rbase + r;
        outp[((size_t)z * SEQ_N + row) * D_MODEL + col] =
            acc[i][j][r] + c_arr[z * SEQ_N + row] * csv;
      }
    }
  }
}

// ---------------- full row softmax (fallback path only) ----------------
__global__ __launch_bounds__(256)
void softmax_kernel(float* __restrict__ attn) {
  const int tid = threadIdx.x;
  float* p = attn + (size_t)blockIdx.x * SEQ_N;
  floatx4* p4 = (floatx4*)p;
  floatx4 x[4];
  float m = -3.402823466e+38f;
#pragma unroll
  for (int c = 0; c < 4; ++c) {
    x[c] = p4[tid + c * 256];
    m = fmaxf(m, fmaxf(fmaxf(x[c][0], x[c][1]), fmaxf(x[c][2], x[c][3])));
  }
#pragma unroll
  for (int o = 32; o; o >>= 1) m = fmaxf(m, __shfl_xor(m, o));
  __shared__ float redm[4], reds[4];
  if ((tid & 63) == 0) redm[tid >> 6] = m;
  __syncthreads();
  m = fmaxf(fmaxf(redm[0], redm[1]), fmaxf(redm[2], redm[3]));
  float s = 0.f;
#pragma unroll
  for (int c = 0; c < 4; ++c)
#pragma unroll
    for (int e = 0; e < 4; ++e) {
      float t = __expf(x[c][e] - m);
      x[c][e] = t;
      s += t;
    }
#pragma unroll
  for (int o = 32; o; o >>= 1) s += __shfl_xor(s, o);
  if ((tid & 63) == 0) reds[tid >> 6] = s;
  __syncthreads();
  s = reds[0] + reds[1] + reds[2] + reds[3];
  float inv = 1.0f / s;
#pragma unroll
  for (int c = 0; c < 4; ++c) {
    floatx4 y;
#pragma unroll
    for (int e = 0; e < 4; ++e) y[e] = x[c][e] * inv;
    p4[tid + c * 256] = y;
  }
}

extern "C" void kernel_launch(void* const* d_in, const int* in_sizes, int n_in,
                              void* d_out, int out_size, void* d_ws, size_t ws_size,
                              hipStream_t stream) {
  const float* x     = (const float*)d_in[0];
  const float* Wq    = (const float*)d_in[1];
  const float* bq    = (const float*)d_in[2];
  const float* Wk    = (const float*)d_in[3];
  const float* bk    = (const float*)d_in[4];
  const float* Wv    = (const float*)d_in[5];
  const float* bv    = (const float*)d_in[6];
  const float* alpha = (const float*)d_in[7];
  const float* lam   = (const float*)d_in[8];

  float* outp  = (float*)d_out;
  float* attnp = outp + (size_t)BATCH * SEQ_N * D_MODEL;
  float* Kp    = attnp + (size_t)BATCH * SEQ_N * SEQ_N;

  const size_t NELEM = (size_t)BATCH * SEQ_N * D_MODEL;   // 8192*1024
  char* ws = (char*)d_ws;
  float* K1d = (float*)ws;                                 // 16 KB
  unsigned short* qb  = (unsigned short*)(ws + 16384);
  unsigned short* kb  = qb + NELEM;
  unsigned short* vT  = kb + NELEM;
  unsigned short* xb  = vT + NELEM;
  unsigned short* wqb = xb + NELEM;
  unsigned short* wkb = wqb + (size_t)D_MODEL * D_MODEL;
  unsigned short* wvb = wkb + (size_t)D_MODEL * D_MODEL;
  float* Sband        = (float*)(wvb + (size_t)D_MODEL * D_MODEL);     // [2][4096][384] f32
  unsigned short* Pb  = (unsigned short*)(Sband + (size_t)BATCH * SEQ_N * BAND);
  float* c_arr        = (float*)(Pb + (size_t)BATCH * SEQ_N * BAND);   // [2][4096]
  float* colsumV      = c_arr + (size_t)BATCH * SEQ_N;                 // [2][1024]

  size_t need = (size_t)((char*)(colsumV + BATCH * D_MODEL) - ws);
  const bool fast = ws_size >= need;

  k1d_kernel<<<16, 256, 0, stream>>>(K1d, alpha, lam);
  writeK_kernel<<<(SEQ_N * SEQ_N / 4) / 256, 256, 0, stream>>>(Kp, K1d);

  if (fast) {
    cvt_bf16_kernel<<<(int)(NELEM / 8 / 256), 256, 0, stream>>>(x, xb, (int)(NELEM / 8));
    cvt_bf16_kernel<<<D_MODEL * D_MODEL / 8 / 256, 256, 0, stream>>>(Wq, wqb, D_MODEL * D_MODEL / 8);
    cvt_bf16_kernel<<<D_MODEL * D_MODEL / 8 / 256, 256, 0, stream>>>(Wk, wkb, D_MODEL * D_MODEL / 8);
    cvt_bf16_kernel<<<D_MODEL * D_MODEL / 8 / 256, 256, 0, stream>>>(Wv, wvb, D_MODEL * D_MODEL / 8);

    gemm_bt<0, 0, 0><<<dim3(D_MODEL / BN, BATCH * SEQ_N / BM, 1), 256, 0, stream>>>(
        xb, D_MODEL, 0, wqb, D_MODEL, 0, qb, D_MODEL, 0, D_MODEL, bq, nullptr);
    gemm_bt<0, 0, 0><<<dim3(D_MODEL / BN, BATCH * SEQ_N / BM, 1), 256, 0, stream>>>(
        xb, D_MODEL, 0, wkb, D_MODEL, 0, kb, D_MODEL, 0, D_MODEL, bk, nullptr);
    gemm_bt<0, 0, 1><<<dim3(BATCH * SEQ_N / BN, D_MODEL / BM, 1), 256, 0, stream>>>(
        wvb, D_MODEL, 0, xb, D_MODEL, 0, vT, BATCH * SEQ_N, 0, D_MODEL, bv, nullptr);

    band_logits<<<dim3(3, SEQ_N / 128, BATCH), 256, 0, stream>>>(qb, kb, Sband, K1d);
    softmax_band<<<BATCH * SEQ_N / 4, 256, 0, stream>>>(Sband, attnp, Pb, c_arr);
    colsumv_kernel<<<BATCH * D_MODEL / 4, 256, 0, stream>>>(vT, colsumV);
    band_pv<<<dim3(D_MODEL / 128, SEQ_N / 128, BATCH), 256, 0, stream>>>(
        Pb, vT, c_arr, colsumV, outp);
  } else {
    // fallback: round-1 proven path
    gemm_bt<1, 1, 0><<<dim3(D_MODEL / BN, BATCH * SEQ_N / BM, 1), 256, 0, stream>>>(
        x, D_MODEL, 0, Wq, D_MODEL, 0, qb, D_MODEL, 0, D_MODEL, bq, nullptr);
    gemm_bt<1, 1, 0><<<dim3(D_MODEL / BN, BATCH * SEQ_N / BM, 1), 256, 0, stream>>>(
        x, D_MODEL, 0, Wk, D_MODEL, 0, kb, D_MODEL, 0, D_MODEL, bk, nullptr);
    gemm_bt<1, 1, 1><<<dim3(BATCH * SEQ_N / BN, D_MODEL / BM, 1), 256, 0, stream>>>(
        Wv, D_MODEL, 0, x, D_MODEL, 0, vT, BATCH * SEQ_N, 0, D_MODEL, bv, nullptr);
    gemm_bt<0, 0, 2><<<dim3(SEQ_N / BN, SEQ_N / BM, BATCH), 256, 0, stream>>>(
        qb, D_MODEL, (long)SEQ_N * D_MODEL, kb, D_MODEL, (long)SEQ_N * D_MODEL,
        attnp, SEQ_N, (long)SEQ_N * SEQ_N, D_MODEL, nullptr, K1d);
    softmax_kernel<<<BATCH * SEQ_N, 256, 0, stream>>>(attnp);
    gemm_bt<1, 0, 3><<<dim3(D_MODEL / BN, SEQ_N / BM, BATCH), 256, 0, stream>>>(
        attnp, SEQ_N, (long)SEQ_N * SEQ_N, vT, BATCH * SEQ_N, (long)SEQ_N,
        outp, D_MODEL, (long)SEQ_N * D_MODEL, SEQ_N, nullptr, nullptr);
  }
}

// Round 4
// 200.523 us; speedup vs baseline: 2.3724x; 1.1009x over previous
//
#include <hip/hip_runtime.h>
#include <hip/hip_bf16.h>
#include <cstdint>
#include <cstddef>

#define D_MODEL 1024
#define SEQ_N   4096
#define BATCH   2
#define BAND    384   // 3 x 128 col-blocks around the diagonal
#define NELEM   ((size_t)BATCH * SEQ_N * D_MODEL)   // 8388608

typedef __attribute__((ext_vector_type(4))) float  floatx4;
typedef __attribute__((ext_vector_type(8))) short  short8;
typedef __attribute__((ext_vector_type(4))) short  short4v;

__device__ __forceinline__ unsigned short f2bf(float f) {
  unsigned u = __float_as_uint(f);
  u += 0x7FFFu + ((u >> 16) & 1u);   // round-to-nearest-even
  return (unsigned short)(u >> 16);
}
__device__ __forceinline__ float bf2f(unsigned short u) {
  return __uint_as_float(((unsigned)u) << 16);
}

// ---------------- fp32 -> bf16 bulk convert (8 elems/thread) ----------------
__global__ __launch_bounds__(256) void cvt_bf16_kernel(const float* __restrict__ src,
                                                       unsigned short* __restrict__ dst,
                                                       int n8) {
  int i = blockIdx.x * 256 + threadIdx.x;
  if (i >= n8) return;
  const floatx4* s4 = (const floatx4*)src;
  floatx4 a = s4[i * 2], b = s4[i * 2 + 1];
  short8 pk;
  pk[0] = (short)f2bf(a[0]); pk[1] = (short)f2bf(a[1]);
  pk[2] = (short)f2bf(a[2]); pk[3] = (short)f2bf(a[3]);
  pk[4] = (short)f2bf(b[0]); pk[5] = (short)f2bf(b[1]);
  pk[6] = (short)f2bf(b[2]); pk[7] = (short)f2bf(b[3]);
  *(short8*)(dst + (size_t)i * 8) = pk;
}

// ---------------- 3 weights -> contiguous bf16 wcat [3072][1024] ----------------
__global__ __launch_bounds__(256)
void cvt3_kernel(const float* __restrict__ a, const float* __restrict__ b,
                 const float* __restrict__ c, unsigned short* __restrict__ dst) {
  const float* src = (blockIdx.z == 0) ? a : (blockIdx.z == 1) ? b : c;
  int i = blockIdx.x * 256 + threadIdx.x;          // 0..131071 (1M/8)
  unsigned short* d = dst + (size_t)blockIdx.z * (D_MODEL * D_MODEL);
  const floatx4* s4 = (const floatx4*)src;
  floatx4 x0 = s4[i * 2], x1 = s4[i * 2 + 1];
  short8 pk;
  pk[0] = (short)f2bf(x0[0]); pk[1] = (short)f2bf(x0[1]);
  pk[2] = (short)f2bf(x0[2]); pk[3] = (short)f2bf(x0[3]);
  pk[4] = (short)f2bf(x1[0]); pk[5] = (short)f2bf(x1[1]);
  pk[6] = (short)f2bf(x1[2]); pk[7] = (short)f2bf(x1[3]);
  *(short8*)(d + (size_t)i * 8) = pk;
}

// ---------------- K1d table + concat bias ----------------
__global__ void k1d_bcat_kernel(float* __restrict__ K1d,
                                const float* __restrict__ alpha_p,
                                const float* __restrict__ lam_p,
                                float* __restrict__ bcat,
                                const float* __restrict__ bq,
                                const float* __restrict__ bk,
                                const float* __restrict__ bv) {
  int t = blockIdx.x * 256 + threadIdx.x;
  if (t < SEQ_N) {
    float a   = fabsf(alpha_p[0]);
    float lam = fabsf(lam_p[0]);
    float rf  = (float)t;
    K1d[t] = powf(rf + 1e-4f, -a) * expf(-rf / lam);
  }
  int u = t - SEQ_N;
  if (u >= 0 && u < 3 * D_MODEL) {
    bcat[u] = (u < D_MODEL) ? bq[u]
            : (u < 2 * D_MODEL) ? bk[u - D_MODEL]
            : bv[u - 2 * D_MODEL];
  }
}

// ---------------- K output: K[i,j] = K1d[|i-j|] ----------------
__global__ __launch_bounds__(256) void writeK_kernel(float* __restrict__ Kout,
                                                     const float* __restrict__ K1d) {
  size_t t = (size_t)blockIdx.x * 256 + threadIdx.x;
  size_t f = t * 4;
  int i = (int)(f >> 12);
  int j = (int)(f & 4095);
  floatx4 v;
#pragma unroll
  for (int e = 0; e < 4; ++e) {
    int d = i - (j + e); d = d < 0 ? -d : d;
    v[e] = K1d[d];
  }
  __builtin_nontemporal_store(v, (floatx4*)(Kout + f));
}

// ---------------- fused QKV gemm: C[m,c] = sum_k xb[m,k]*wcat[c,k] + bcat[c] ----------------
// cols 0..1023 -> qb row-major; 1024..2047 -> kb row-major; 2048..3071 -> vT transposed
__global__ __launch_bounds__(256)
void qkv_gemm(const unsigned short* __restrict__ xb,     // [8192][1024]
              const unsigned short* __restrict__ wcat,   // [3072][1024]
              const float* __restrict__ bcat,            // [3072]
              unsigned short* __restrict__ qb,           // [8192][1024]; kb = qb+NELEM
              unsigned short* __restrict__ vT)           // [1024][8192]
{
  __shared__ unsigned short As[128 * 32];
  __shared__ unsigned short Bs[128 * 32];
  const int tid = threadIdx.x, lane = tid & 63, wave = tid >> 6;

  int gx = (int)gridDim.x, gy = (int)gridDim.y;
  int total = gx * gy;                                   // 1536, %8==0
  int flat  = (int)blockIdx.y * gx + (int)blockIdx.x;
  int w     = (flat & 7) * (total >> 3) + (flat >> 3);
  int bx = w % gx, by = w / gx;
  const int bm0 = by * 128;      // row in 8192
  const int bn0 = bx * 128;      // col in 3072
  const int wm = (wave >> 1) * 64, wn = (wave & 1) * 64;

  floatx4 acc[4][4] = {};
  for (int k0 = 0; k0 < D_MODEL; k0 += 32) {
#pragma unroll
    for (int t = 0; t < 2; ++t) {
      int bu = wave * 64 + t * 256;
      int u  = bu + lane;
      const unsigned short* srcA = xb + (size_t)(bm0 + (u >> 2)) * D_MODEL + k0 + (u & 3) * 8;
      __builtin_amdgcn_global_load_lds((const __attribute__((address_space(1))) void*)srcA,
                                       (__attribute__((address_space(3))) void*)(As + bu * 8), 16, 0, 0);
      const unsigned short* srcB = wcat + (size_t)(bn0 + (u >> 2)) * D_MODEL + k0 + (u & 3) * 8;
      __builtin_amdgcn_global_load_lds((const __attribute__((address_space(1))) void*)srcB,
                                       (__attribute__((address_space(3))) void*)(Bs + bu * 8), 16, 0, 0);
    }
    __syncthreads();
    short8 af[4], bf[4];
#pragma unroll
    for (int i = 0; i < 4; ++i)
      af[i] = *(const short8*)(As + (wm + i * 16 + (lane & 15)) * 32 + (lane >> 4) * 8);
#pragma unroll
    for (int j = 0; j < 4; ++j)
      bf[j] = *(const short8*)(Bs + (wn + j * 16 + (lane & 15)) * 32 + (lane >> 4) * 8);
#pragma unroll
    for (int i = 0; i < 4; ++i)
#pragma unroll
      for (int j = 0; j < 4; ++j)
        acc[i][j] = __builtin_amdgcn_mfma_f32_16x16x32_bf16(af[i], bf[j], acc[i][j], 0, 0, 0);
    __syncthreads();
  }

#pragma unroll
  for (int i = 0; i < 4; ++i) {
#pragma unroll
    for (int j = 0; j < 4; ++j) {
      int col   = bn0 + wn + j * 16 + (lane & 15);
      int rbase = bm0 + wm + i * 16 + (lane >> 4) * 4;
      float b = bcat[col];
      if (col < 2048) {                         // q or k: row-major scalar stores
        unsigned short* C = qb + ((col >= D_MODEL) ? NELEM : 0);
        int cr = col & (D_MODEL - 1);
#pragma unroll
        for (int r = 0; r < 4; ++r)
          C[(size_t)(rbase + r) * D_MODEL + cr] = f2bf(acc[i][j][r] + b);
      } else {                                  // v: transposed, 4 rows contiguous
        int e = col - 2048;
        short4v pk;
#pragma unroll
        for (int r = 0; r < 4; ++r) pk[r] = (short)f2bf(acc[i][j][r] + b);
        *(short4v*)(vT + (size_t)e * (BATCH * SEQ_N) + rbase) = pk;
      }
    }
  }
}

// ---------------- generic gemm_bt (fallback path) ----------------
#define BM 128
#define BN 128
#define BK 32

template<int ASRC, int BSRC, int EPI>
__global__ __launch_bounds__(256)
void gemm_bt(const void* __restrict__ Ap_, int lda, long sA,
             const void* __restrict__ Bp_, int ldb, long sB,
             void* __restrict__ Cp_, int ldc, long sC,
             int K, const float* __restrict__ bias,
             const float* __restrict__ K1d)
{
  __shared__ unsigned short As[BM * BK];
  __shared__ unsigned short Bs[BN * BK];
  const int tid  = threadIdx.x;
  const int lane = tid & 63;
  const int wave = tid >> 6;

  int gx = (int)gridDim.x, gy = (int)gridDim.y;
  int total = gx * gy * (int)gridDim.z;
  int flat  = (int)blockIdx.z * gx * gy + (int)blockIdx.y * gx + (int)blockIdx.x;
  int w     = (flat & 7) * (total >> 3) + (flat >> 3);
  int bx = w % gx;
  int t_ = w / gx;
  int by = t_ % gy;
  int z  = t_ / gy;

  const int bm0  = by * BM;
  const int bn0  = bx * BN;
  const int wm   = (wave >> 1) * 64;
  const int wn   = (wave & 1) * 64;

  floatx4 acc[4][4] = {};

  const unsigned short* Agb = (const unsigned short*)Ap_ + (size_t)z * (size_t)sA;
  const float*          Agf = (const float*)Ap_          + (size_t)z * (size_t)sA;
  const unsigned short* Bgb = (const unsigned short*)Bp_ + (size_t)z * (size_t)sB;
  const float*          Bgf = (const float*)Bp_          + (size_t)z * (size_t)sB;

  for (int k0 = 0; k0 < K; k0 += BK) {
    if constexpr (ASRC == 0) {
#pragma unroll
      for (int t = 0; t < 2; ++t) {
        int bu = wave * 64 + t * 256;
        int u  = bu + lane;
        const unsigned short* src = Agb + (size_t)(bm0 + (u >> 2)) * lda + k0 + (u & 3) * 8;
        __builtin_amdgcn_global_load_lds((const __attribute__((address_space(1))) void*)src,
                                         (__attribute__((address_space(3))) void*)(As + bu * 8),
                                         16, 0, 0);
      }
    } else {
#pragma unroll
      for (int t = 0; t < 2; ++t) {
        int u = tid + t * 256;
        const float* src = Agf + (size_t)(bm0 + (u >> 2)) * lda + k0 + (u & 3) * 8;
        floatx4 x0 = *(const floatx4*)src;
        floatx4 x1 = *(const floatx4*)(src + 4);
        short8 pk;
        pk[0] = (short)f2bf(x0[0]); pk[1] = (short)f2bf(x0[1]);
        pk[2] = (short)f2bf(x0[2]); pk[3] = (short)f2bf(x0[3]);
        pk[4] = (short)f2bf(x1[0]); pk[5] = (short)f2bf(x1[1]);
        pk[6] = (short)f2bf(x1[2]); pk[7] = (short)f2bf(x1[3]);
        *(short8*)(As + u * 8) = pk;
      }
    }
    if constexpr (BSRC == 0) {
#pragma unroll
      for (int t = 0; t < 2; ++t) {
        int bu = wave * 64 + t * 256;
        int u  = bu + lane;
        const unsigned short* src = Bgb + (size_t)(bn0 + (u >> 2)) * ldb + k0 + (u & 3) * 8;
        __builtin_amdgcn_global_load_lds((const __attribute__((address_space(1))) void*)src,
                                         (__attribute__((address_space(3))) void*)(Bs + bu * 8),
                                         16, 0, 0);
      }
    } else {
#pragma unroll
      for (int t = 0; t < 2; ++t) {
        int u = tid + t * 256;
        const float* src = Bgf + (size_t)(bn0 + (u >> 2)) * ldb + k0 + (u & 3) * 8;
        floatx4 x0 = *(const floatx4*)src;
        floatx4 x1 = *(const floatx4*)(src + 4);
        short8 pk;
        pk[0] = (short)f2bf(x0[0]); pk[1] = (short)f2bf(x0[1]);
        pk[2] = (short)f2bf(x0[2]); pk[3] = (short)f2bf(x0[3]);
        pk[4] = (short)f2bf(x1[0]); pk[5] = (short)f2bf(x1[1]);
        pk[6] = (short)f2bf(x1[2]); pk[7] = (short)f2bf(x1[3]);
        *(short8*)(Bs + u * 8) = pk;
      }
    }
    __syncthreads();

    short8 af[4], bf[4];
#pragma unroll
    for (int i = 0; i < 4; ++i)
      af[i] = *(const short8*)(As + (wm + i * 16 + (lane & 15)) * BK + (lane >> 4) * 8);
#pragma unroll
    for (int j = 0; j < 4; ++j)
      bf[j] = *(const short8*)(Bs + (wn + j * 16 + (lane & 15)) * BK + (lane >> 4) * 8);
#pragma unroll
    for (int i = 0; i < 4; ++i)
#pragma unroll
      for (int j = 0; j < 4; ++j)
        acc[i][j] = __builtin_amdgcn_mfma_f32_16x16x32_bf16(af[i], bf[j], acc[i][j], 0, 0, 0);
    __syncthreads();
  }

  const int col0 = bn0 + wn;
  const int row0 = bm0 + wm;
#pragma unroll
  for (int i = 0; i < 4; ++i) {
#pragma unroll
    for (int j = 0; j < 4; ++j) {
      int col   = col0 + j * 16 + (lane & 15);
      int rbase = row0 + i * 16 + (lane >> 4) * 4;
      if constexpr (EPI == 0) {
        unsigned short* C = (unsigned short*)Cp_ + (size_t)z * (size_t)sC;
        float b = bias[col];
#pragma unroll
        for (int r = 0; r < 4; ++r)
          C[(size_t)(rbase + r) * ldc + col] = f2bf(acc[i][j][r] + b);
      } else if constexpr (EPI == 1) {
        unsigned short* C = (unsigned short*)Cp_ + (size_t)z * (size_t)sC;
#pragma unroll
        for (int r = 0; r < 4; ++r)
          C[(size_t)(rbase + r) * ldc + col] = f2bf(acc[i][j][r] + bias[rbase + r]);
      } else if constexpr (EPI == 2) {
        float* C = (float*)Cp_ + (size_t)z * (size_t)sC;
#pragma unroll
        for (int r = 0; r < 4; ++r) {
          int row = rbase + r;
          int d = row - col; d = d < 0 ? -d : d;
          C[(size_t)row * ldc + col] = acc[i][j][r] * 0.03125f * K1d[d];
        }
      } else {
        float* C = (float*)Cp_ + (size_t)z * (size_t)sC;
#pragma unroll
        for (int r = 0; r < 4; ++r)
          C[(size_t)(rbase + r) * ldc + col] = acc[i][j][r];
      }
    }
  }
}

// ---------------- band logits ----------------
__global__ __launch_bounds__(256)
void band_logits(const unsigned short* __restrict__ Q,
                 const unsigned short* __restrict__ Kb,
                 float* __restrict__ Sband,
                 const float* __restrict__ K1d)
{
  __shared__ unsigned short As[128 * 32];
  __shared__ unsigned short Bs[128 * 32];
  const int tid = threadIdx.x, lane = tid & 63, wave = tid >> 6;
  const int bx = blockIdx.x;            // 0..2  (band third)
  const int by = blockIdx.y;            // 0..31 (row block)
  const int z  = blockIdx.z;
  const int bm0 = by * 128;
  const int bn0 = (by + bx - 1) * 128;
  const bool live = (unsigned)bn0 < (unsigned)SEQ_N;
  const int wm = (wave >> 1) * 64, wn = (wave & 1) * 64;
  floatx4 acc[4][4] = {};

  if (live) {
    const unsigned short* Ag = Q  + (size_t)z * SEQ_N * D_MODEL;
    const unsigned short* Bg = Kb + (size_t)z * SEQ_N * D_MODEL;
    for (int k0 = 0; k0 < D_MODEL; k0 += 32) {
#pragma unroll
      for (int t = 0; t < 2; ++t) {
        int bu = wave * 64 + t * 256;
        int u  = bu + lane;
        const unsigned short* srcA = Ag + (size_t)(bm0 + (u >> 2)) * D_MODEL + k0 + (u & 3) * 8;
        __builtin_amdgcn_global_load_lds((const __attribute__((address_space(1))) void*)srcA,
                                         (__attribute__((address_space(3))) void*)(As + bu * 8), 16, 0, 0);
        const unsigned short* srcB = Bg + (size_t)(bn0 + (u >> 2)) * D_MODEL + k0 + (u & 3) * 8;
        __builtin_amdgcn_global_load_lds((const __attribute__((address_space(1))) void*)srcB,
                                         (__attribute__((address_space(3))) void*)(Bs + bu * 8), 16, 0, 0);
      }
      __syncthreads();
      short8 af[4], bf[4];
#pragma unroll
      for (int i = 0; i < 4; ++i)
        af[i] = *(const short8*)(As + (wm + i * 16 + (lane & 15)) * 32 + (lane >> 4) * 8);
#pragma unroll
      for (int j = 0; j < 4; ++j)
        bf[j] = *(const short8*)(Bs + (wn + j * 16 + (lane & 15)) * 32 + (lane >> 4) * 8);
#pragma unroll
      for (int i = 0; i < 4; ++i)
#pragma unroll
        for (int j = 0; j < 4; ++j)
          acc[i][j] = __builtin_amdgcn_mfma_f32_16x16x32_bf16(af[i], bf[j], acc[i][j], 0, 0, 0);
      __syncthreads();
    }
  }

  float* Cb = Sband + ((size_t)z * SEQ_N + bm0) * BAND + bx * 128;
#pragma unroll
  for (int i = 0; i < 4; ++i) {
#pragma unroll
    for (int j = 0; j < 4; ++j) {
      int cl  = wn + j * 16 + (lane & 15);
      int rl0 = wm + i * 16 + (lane >> 4) * 4;
#pragma unroll
      for (int r = 0; r < 4; ++r) {
        float v = 0.f;
        if (live) {
          int d = (bm0 + rl0 + r) - (bn0 + cl); d = d < 0 ? -d : d;
          v = acc[i][j][r] * 0.03125f * K1d[d];
        }
        Cb[(size_t)(rl0 + r) * BAND + cl] = v;
      }
    }
  }
}

// ---------------- band softmax: full attn row + bf16 (P-c) band + c ----------------
__global__ __launch_bounds__(256)
void softmax_band(const float* __restrict__ Sband,
                  float* __restrict__ attn,
                  unsigned short* __restrict__ Pb,
                  float* __restrict__ c_arr)
{
  __shared__ float lds_e[4][BAND];
  const int lane = threadIdx.x & 63, wave = threadIdx.x >> 6;
  const int gi = blockIdx.x * 4 + wave;     // 0..8191
  const int ii = gi & (SEQ_N - 1);
  const int bi = ii >> 7;
  const int cbase = bi * 128 - 128;
  const float* S = Sband + (size_t)gi * BAND;

  float sv[6];
  float m = 0.0f;
#pragma unroll
  for (int j = 0; j < 6; ++j) {
    int t = j * 64 + lane;
    int col = cbase + t;
    sv[j] = S[t];
    if ((unsigned)col < (unsigned)SEQ_N) m = fmaxf(m, sv[j]);
  }
#pragma unroll
  for (int o = 32; o; o >>= 1) m = fmaxf(m, __shfl_xor(m, o));

  float s = 0.f;
#pragma unroll
  for (int j = 0; j < 6; ++j) {
    int t = j * 64 + lane;
    int col = cbase + t;
    float e = ((unsigned)col < (unsigned)SEQ_N) ? __expf(sv[j] - m) : 0.f;
    sv[j] = e;
    s += e;
  }
#pragma unroll
  for (int o = 32; o; o >>= 1) s += __shfl_xor(s, o);

  int n_valid = BAND - ((bi == 0) ? 128 : 0) - ((bi == 31) ? 128 : 0);
  float efar  = __expf(-m);
  float denom = s + (float)(SEQ_N - n_valid) * efar;
  float inv   = 1.0f / denom;
  float c     = efar * inv;

  unsigned short* prow = Pb + (size_t)gi * BAND;
#pragma unroll
  for (int j = 0; j < 6; ++j) {
    int t = j * 64 + lane;
    float p = sv[j] * inv;
    lds_e[wave][t] = p;
    int col = cbase + t;
    prow[t] = ((unsigned)col < (unsigned)SEQ_N) ? f2bf(p - c) : (unsigned short)0;
  }
  if (lane == 0) c_arr[gi] = c;

  float* arow = attn + (size_t)gi * SEQ_N;
#pragma unroll
  for (int jj = 0; jj < 16; ++jj) {
    int col0 = jj * 256 + lane * 4;
    floatx4 o;
#pragma unroll
    for (int e = 0; e < 4; ++e) {
      int t = col0 + e - cbase;
      o[e] = ((unsigned)t < (unsigned)BAND) ? lds_e[wave][t] : c;
    }
    __builtin_nontemporal_store(o, (floatx4*)(arow + col0));
  }
}

// ---------------- colsumV[b][d] = sum_n vT[d][b*4096+n] ----------------
__global__ __launch_bounds__(256)
void colsumv_kernel(const unsigned short* __restrict__ vT, float* __restrict__ colsumV) {
  const int lane = threadIdx.x & 63, wave = threadIdx.x >> 6;
  const int idx = blockIdx.x * 4 + wave;     // 0..2047
  const int d = idx >> 1, b = idx & 1;
  const unsigned short* p = vT + (size_t)d * (BATCH * SEQ_N) + b * SEQ_N;
  float s = 0.f;
#pragma unroll
  for (int it = 0; it < 8; ++it) {
    short8 v = *(const short8*)(p + (size_t)(it * 512 + lane * 8));
#pragma unroll
    for (int e = 0; e < 8; ++e) s += bf2f((unsigned short)v[e]);
  }
#pragma unroll
  for (int o = 32; o; o >>= 1) s += __shfl_xor(s, o);
  if (lane == 0) colsumV[b * D_MODEL + d] = s;
}

// ---------------- band PV: out = (P-c) @ V_band + c * colsumV ----------------
__global__ __launch_bounds__(256)
void band_pv(const unsigned short* __restrict__ Pb,   // [2][4096][384]
             const unsigned short* __restrict__ vT,   // [1024][8192]
             const float* __restrict__ c_arr,         // [2][4096]
             const float* __restrict__ colsumV,       // [2][1024]
             float* __restrict__ outp)                // [2][4096][1024]
{
  __shared__ unsigned short As[128 * 32];
  __shared__ unsigned short Bs[128 * 32];
  const int tid = threadIdx.x, lane = tid & 63, wave = tid >> 6;
  const int bx = blockIdx.x;     // 0..7  d-block
  const int by = blockIdx.y;     // 0..31 row-block
  const int z  = blockIdx.z;
  const int bm0 = by * 128;
  const int bn0 = bx * 128;
  const int wm = (wave >> 1) * 64, wn = (wave & 1) * 64;

  const unsigned short* Ag = Pb + ((size_t)z * SEQ_N + bm0) * BAND;
  // B row d, band col t -> vT[d][z*4096 + by*128 - 128 + t]; slight pre/post
  // overrun lands in adjacent ws buffers (finite bf16, multiplied by P==0).
  const unsigned short* Bg = vT + ((long)z * SEQ_N + (long)by * 128 - 128);

  floatx4 acc[4][4] = {};
  for (int k0 = 0; k0 < BAND; k0 += 32) {
#pragma unroll
    for (int t = 0; t < 2; ++t) {
      int bu = wave * 64 + t * 256;
      int u  = bu + lane;
      const unsigned short* srcA = Ag + (size_t)(u >> 2) * BAND + k0 + (u & 3) * 8;
      __builtin_amdgcn_global_load_lds((const __attribute__((address_space(1))) void*)srcA,
                                       (__attribute__((address_space(3))) void*)(As + bu * 8), 16, 0, 0);
      const unsigned short* srcB = Bg + (size_t)(bn0 + (u >> 2)) * (BATCH * SEQ_N) + k0 + (u & 3) * 8;
      __builtin_amdgcn_global_load_lds((const __attribute__((address_space(1))) void*)srcB,
                                       (__attribute__((address_space(3))) void*)(Bs + bu * 8), 16, 0, 0);
    }
    __syncthreads();
    short8 af[4], bf[4];
#pragma unroll
    for (int i = 0; i < 4; ++i)
      af[i] = *(const short8*)(As + (wm + i * 16 + (lane & 15)) * 32 + (lane >> 4) * 8);
#pragma unroll
    for (int j = 0; j < 4; ++j)
      bf[j] = *(const short8*)(Bs + (wn + j * 16 + (lane & 15)) * 32 + (lane >> 4) * 8);
#pragma unroll
    for (int i = 0; i < 4; ++i)
#pragma unroll
      for (int j = 0; j < 4; ++j)
        acc[i][j] = __builtin_amdgcn_mfma_f32_16x16x32_bf16(af[i], bf[j], acc[i][j], 0, 0, 0);
    __syncthreads();
  }

#pragma unroll
  for (int i = 0; i < 4; ++i) {
#pragma unroll
    for (int j = 0; j < 4; ++j) {
      int col   = bn0 + wn + j * 16 + (lane & 15);
      int rbase = bm0 + wm + i * 16 + (lane >> 4) * 4;
      float csv = colsumV[z * D_MODEL + col];
#pragma unroll
      for (int r = 0; r < 4; ++r) {
        int row = rbase + r;
        float o = acc[i][j][r] + c_arr[z * SEQ_N + row] * csv;
        __builtin_nontemporal_store(o, outp + ((size_t)z * SEQ_N + row) * D_MODEL + col);
      }
    }
  }
}

// ---------------- full row softmax (fallback path only) ----------------
__global__ __launch_bounds__(256)
void softmax_kernel(float* __restrict__ attn) {
  const int tid = threadIdx.x;
  float* p = attn + (size_t)blockIdx.x * SEQ_N;
  floatx4* p4 = (floatx4*)p;
  floatx4 x[4];
  float m = -3.402823466e+38f;
#pragma unroll
  for (int c = 0; c < 4; ++c) {
    x[c] = p4[tid + c * 256];
    m = fmaxf(m, fmaxf(fmaxf(x[c][0], x[c][1]), fmaxf(x[c][2], x[c][3])));
  }
#pragma unroll
  for (int o = 32; o; o >>= 1) m = fmaxf(m, __shfl_xor(m, o));
  __shared__ float redm[4], reds[4];
  if ((tid & 63) == 0) redm[tid >> 6] = m;
  __syncthreads();
  m = fmaxf(fmaxf(redm[0], redm[1]), fmaxf(redm[2], redm[3]));
  float s = 0.f;
#pragma unroll
  for (int c = 0; c < 4; ++c)
#pragma unroll
    for (int e = 0; e < 4; ++e) {
      float t = __expf(x[c][e] - m);
      x[c][e] = t;
      s += t;
    }
#pragma unroll
  for (int o = 32; o; o >>= 1) s += __shfl_xor(s, o);
  if ((tid & 63) == 0) reds[tid >> 6] = s;
  __syncthreads();
  s = reds[0] + reds[1] + reds[2] + reds[3];
  float inv = 1.0f / s;
#pragma unroll
  for (int c = 0; c < 4; ++c) {
    floatx4 y;
#pragma unroll
    for (int e = 0; e < 4; ++e) y[e] = x[c][e] * inv;
    p4[tid + c * 256] = y;
  }
}

extern "C" void kernel_launch(void* const* d_in, const int* in_sizes, int n_in,
                              void* d_out, int out_size, void* d_ws, size_t ws_size,
                              hipStream_t stream) {
  const float* x     = (const float*)d_in[0];
  const float* Wq    = (const float*)d_in[1];
  const float* bq    = (const float*)d_in[2];
  const float* Wk    = (const float*)d_in[3];
  const float* bk    = (const float*)d_in[4];
  const float* Wv    = (const float*)d_in[5];
  const float* bv    = (const float*)d_in[6];
  const float* alpha = (const float*)d_in[7];
  const float* lam   = (const float*)d_in[8];

  float* outp  = (float*)d_out;
  float* attnp = outp + (size_t)BATCH * SEQ_N * D_MODEL;
  float* Kp    = attnp + (size_t)BATCH * SEQ_N * SEQ_N;

  char* ws = (char*)d_ws;
  float* K1d = (float*)ws;                                 // 16 KB
  unsigned short* qb  = (unsigned short*)(ws + 16384);     // [8192][1024]
  unsigned short* kb  = qb + NELEM;                        // [8192][1024]
  unsigned short* vT  = kb + NELEM;                        // [1024][8192]
  unsigned short* xb  = vT + NELEM;                        // [8192][1024]
  unsigned short* wcat = xb + NELEM;                       // [3072][1024]
  float* Sband        = (float*)(wcat + (size_t)3 * D_MODEL * D_MODEL); // [2][4096][384]
  unsigned short* Pb  = (unsigned short*)(Sband + (size_t)BATCH * SEQ_N * BAND);
  float* c_arr        = (float*)(Pb + (size_t)BATCH * SEQ_N * BAND);   // [2][4096]
  float* colsumV      = c_arr + (size_t)BATCH * SEQ_N;                 // [2][1024]
  float* bcat         = colsumV + (size_t)BATCH * D_MODEL;             // [3072]

  size_t need = (size_t)((char*)(bcat + 3 * D_MODEL) - ws);
  const bool fast = ws_size >= need;

  if (fast) {
    k1d_bcat_kernel<<<28, 256, 0, stream>>>(K1d, alpha, lam, bcat, bq, bk, bv);
    writeK_kernel<<<(SEQ_N * SEQ_N / 4) / 256, 256, 0, stream>>>(Kp, K1d);
    cvt_bf16_kernel<<<(int)(NELEM / 8 / 256), 256, 0, stream>>>(x, xb, (int)(NELEM / 8));
    cvt3_kernel<<<dim3(D_MODEL * D_MODEL / 8 / 256, 1, 3), 256, 0, stream>>>(Wq, Wk, Wv, wcat);

    qkv_gemm<<<dim3(3 * D_MODEL / 128, BATCH * SEQ_N / 128), 256, 0, stream>>>(
        xb, wcat, bcat, qb, vT);

    colsumv_kernel<<<BATCH * D_MODEL / 4, 256, 0, stream>>>(vT, colsumV);
    band_logits<<<dim3(3, SEQ_N / 128, BATCH), 256, 0, stream>>>(qb, kb, Sband, K1d);
    softmax_band<<<BATCH * SEQ_N / 4, 256, 0, stream>>>(Sband, attnp, Pb, c_arr);
    band_pv<<<dim3(D_MODEL / 128, SEQ_N / 128, BATCH), 256, 0, stream>>>(
        Pb, vT, c_arr, colsumV, outp);
  } else {
    // fallback: round-1 proven path
    k1d_bcat_kernel<<<28, 256, 0, stream>>>(K1d, alpha, lam, (float*)(ws + 8192), bq, bk, bv);
    writeK_kernel<<<(SEQ_N * SEQ_N / 4) / 256, 256, 0, stream>>>(Kp, K1d);
    gemm_bt<1, 1, 0><<<dim3(D_MODEL / BN, BATCH * SEQ_N / BM, 1), 256, 0, stream>>>(
        x, D_MODEL, 0, Wq, D_MODEL, 0, qb, D_MODEL, 0, D_MODEL, bq, nullptr);
    gemm_bt<1, 1, 0><<<dim3(D_MODEL / BN, BATCH * SEQ_N / BM, 1), 256, 0, stream>>>(
        x, D_MODEL, 0, Wk, D_MODEL, 0, kb, D_MODEL, 0, D_MODEL, bk, nullptr);
    gemm_bt<1, 1, 1><<<dim3(BATCH * SEQ_N / BN, D_MODEL / BM, 1), 256, 0, stream>>>(
        Wv, D_MODEL, 0, x, D_MODEL, 0, vT, BATCH * SEQ_N, 0, D_MODEL, bv, nullptr);
    gemm_bt<0, 0, 2><<<dim3(SEQ_N / BN, SEQ_N / BM, BATCH), 256, 0, stream>>>(
        qb, D_MODEL, (long)SEQ_N * D_MODEL, kb, D_MODEL, (long)SEQ_N * D_MODEL,
        attnp, SEQ_N, (long)SEQ_N * SEQ_N, D_MODEL, nullptr, K1d);
    softmax_kernel<<<BATCH * SEQ_N, 256, 0, stream>>>(attnp);
    gemm_bt<1, 0, 3><<<dim3(D_MODEL / BN, SEQ_N / BM, BATCH), 256, 0, stream>>>(
        attnp, SEQ_N, (long)SEQ_N * SEQ_N, vT, BATCH * SEQ_N, (long)SEQ_N,
        outp, D_MODEL, (long)SEQ_N * D_MODEL, SEQ_N, nullptr, nullptr);
  }
}

// Round 5
// 182.086 us; speedup vs baseline: 2.6126x; 1.1013x over previous
//
#include <hip/hip_runtime.h>
#include <hip/hip_bf16.h>
#include <cstdint>
#include <cstddef>

#define D_MODEL 1024
#define SEQ_N   4096
#define BATCH   2
#define BAND    256   // 4 x 64-col blocks, window [g*64-64, g*64+192) per 64-row group g
#define NELEM   ((size_t)BATCH * SEQ_N * D_MODEL)   // 8388608

typedef __attribute__((ext_vector_type(4))) float  floatx4;
typedef __attribute__((ext_vector_type(8))) short  short8;
typedef __attribute__((ext_vector_type(4))) short  short4v;

__device__ __forceinline__ unsigned short f2bf(float f) {
  unsigned u = __float_as_uint(f);
  u += 0x7FFFu + ((u >> 16) & 1u);   // round-to-nearest-even
  return (unsigned short)(u >> 16);
}
__device__ __forceinline__ float bf2f(unsigned short u) {
  return __uint_as_float(((unsigned)u) << 16);
}

// ---------------- fused prep: x->xb, {Wq,Wk,Wv}->wcat, K1d, bcat ----------------
__global__ __launch_bounds__(256)
void fused_prep(const float* __restrict__ x,
                const float* __restrict__ Wq, const float* __restrict__ Wk,
                const float* __restrict__ Wv,
                const float* __restrict__ bq, const float* __restrict__ bk,
                const float* __restrict__ bv,
                const float* __restrict__ alpha_p, const float* __restrict__ lam_p,
                unsigned short* __restrict__ xb, unsigned short* __restrict__ wcat,
                float* __restrict__ bcat, float* __restrict__ K1d)
{
  int bid = blockIdx.x, tid = threadIdx.x;
  if (bid < 4096) {                       // x -> xb  (1048576 units of 8)
    int i = bid * 256 + tid;
    const floatx4* s4 = (const floatx4*)x;
    floatx4 a = s4[i * 2], b = s4[i * 2 + 1];
    short8 pk;
    pk[0] = (short)f2bf(a[0]); pk[1] = (short)f2bf(a[1]);
    pk[2] = (short)f2bf(a[2]); pk[3] = (short)f2bf(a[3]);
    pk[4] = (short)f2bf(b[0]); pk[5] = (short)f2bf(b[1]);
    pk[6] = (short)f2bf(b[2]); pk[7] = (short)f2bf(b[3]);
    *(short8*)(xb + (size_t)i * 8) = pk;
  } else if (bid < 5632) {                // weights -> wcat
    int u = bid - 4096;                   // 0..1535
    int z = u >> 9;
    int i = (u & 511) * 256 + tid;        // < 131072
    const float* src = (z == 0) ? Wq : (z == 1) ? Wk : Wv;
    unsigned short* d = wcat + (size_t)z * (D_MODEL * D_MODEL);
    const floatx4* s4 = (const floatx4*)src;
    floatx4 a = s4[i * 2], b = s4[i * 2 + 1];
    short8 pk;
    pk[0] = (short)f2bf(a[0]); pk[1] = (short)f2bf(a[1]);
    pk[2] = (short)f2bf(a[2]); pk[3] = (short)f2bf(a[3]);
    pk[4] = (short)f2bf(b[0]); pk[5] = (short)f2bf(b[1]);
    pk[6] = (short)f2bf(b[2]); pk[7] = (short)f2bf(b[3]);
    *(short8*)(d + (size_t)i * 8) = pk;
  } else {                                // K1d + bcat
    int t = (bid - 5632) * 256 + tid;     // 0..7167
    if (t < SEQ_N) {
      float a   = fabsf(alpha_p[0]);
      float lam = fabsf(lam_p[0]);
      float rf  = (float)t;
      K1d[t] = powf(rf + 1e-4f, -a) * expf(-rf / lam);
    }
    int v = t - SEQ_N;
    if (v >= 0 && v < 3 * D_MODEL) {
      bcat[v] = (v < D_MODEL) ? bq[v]
              : (v < 2 * D_MODEL) ? bk[v - D_MODEL]
              : bv[v - 2 * D_MODEL];
    }
  }
}

// ---------------- K1d (fallback path) ----------------
__global__ void k1d_kernel(float* __restrict__ K1d,
                           const float* __restrict__ alpha_p,
                           const float* __restrict__ lam_p) {
  int r = blockIdx.x * blockDim.x + threadIdx.x;
  if (r >= SEQ_N) return;
  float a   = fabsf(alpha_p[0]);
  float lam = fabsf(lam_p[0]);
  float rf  = (float)r;
  K1d[r] = powf(rf + 1e-4f, -a) * expf(-rf / lam);
}

// ---------------- K output: K[i,j] = K1d[|i-j|] ----------------
__global__ __launch_bounds__(256) void writeK_kernel(float* __restrict__ Kout,
                                                     const float* __restrict__ K1d) {
  size_t t = (size_t)blockIdx.x * 256 + threadIdx.x;
  size_t f = t * 4;
  int i = (int)(f >> 12);
  int j = (int)(f & 4095);
  floatx4 v;
#pragma unroll
  for (int e = 0; e < 4; ++e) {
    int d = i - (j + e); d = d < 0 ? -d : d;
    v[e] = K1d[d];
  }
  __builtin_nontemporal_store(v, (floatx4*)(Kout + f));
}

// ---------------- qkv_qk: q/k cols, swapped-operand MFMA -> 8B stores ----------------
__global__ __launch_bounds__(256)
void qkv_qk(const unsigned short* __restrict__ xb,     // [8192][1024]
            const unsigned short* __restrict__ wcat,   // [3072][1024] (rows 0..2047 used)
            const float* __restrict__ bcat,            // [3072]
            unsigned short* __restrict__ qb)           // [8192][1024]; kb = qb+NELEM
{
  __shared__ unsigned short As[128 * 32];
  __shared__ unsigned short Bs[128 * 32];
  const int tid = threadIdx.x, lane = tid & 63, wave = tid >> 6;

  int gx = (int)gridDim.x, gy = (int)gridDim.y;
  int total = gx * gy;                                 // 1024, %8==0
  int flat  = (int)blockIdx.y * gx + (int)blockIdx.x;
  int w     = (flat & 7) * (total >> 3) + (flat >> 3);
  int bx = w % gx, by = w / gx;
  const int bm0 = by * 128;      // x row
  const int bn0 = bx * 128;      // w col in [0,2048)
  const int wm = (wave >> 1) * 64, wn = (wave & 1) * 64;

  floatx4 acc[4][4] = {};
  for (int k0 = 0; k0 < D_MODEL; k0 += 32) {
#pragma unroll
    for (int t = 0; t < 2; ++t) {
      int bu = wave * 64 + t * 256;
      int u  = bu + lane;
      const unsigned short* srcA = xb + (size_t)(bm0 + (u >> 2)) * D_MODEL + k0 + (u & 3) * 8;
      __builtin_amdgcn_global_load_lds((const __attribute__((address_space(1))) void*)srcA,
                                       (__attribute__((address_space(3))) void*)(As + bu * 8), 16, 0, 0);
      const unsigned short* srcB = wcat + (size_t)(bn0 + (u >> 2)) * D_MODEL + k0 + (u & 3) * 8;
      __builtin_amdgcn_global_load_lds((const __attribute__((address_space(1))) void*)srcB,
                                       (__attribute__((address_space(3))) void*)(Bs + bu * 8), 16, 0, 0);
    }
    __syncthreads();
    short8 af[4], bf[4];
#pragma unroll
    for (int i = 0; i < 4; ++i)
      af[i] = *(const short8*)(As + (wm + i * 16 + (lane & 15)) * 32 + (lane >> 4) * 8);
#pragma unroll
    for (int j = 0; j < 4; ++j)
      bf[j] = *(const short8*)(Bs + (wn + j * 16 + (lane & 15)) * 32 + (lane >> 4) * 8);
#pragma unroll
    for (int i = 0; i < 4; ++i)
#pragma unroll
      for (int j = 0; j < 4; ++j)   // SWAPPED operands: lane&15 <-> x-row, reg r <-> w-col
        acc[i][j] = __builtin_amdgcn_mfma_f32_16x16x32_bf16(bf[j], af[i], acc[i][j], 0, 0, 0);
    __syncthreads();
  }

#pragma unroll
  for (int i = 0; i < 4; ++i) {
#pragma unroll
    for (int j = 0; j < 4; ++j) {
      int xrow = bm0 + wm + i * 16 + (lane & 15);
      int n0   = bn0 + wn + j * 16 + (lane >> 4) * 4;   // w col base, 4 consecutive
      floatx4 b4 = *(const floatx4*)(bcat + n0);
      unsigned short* C = qb + ((n0 >= D_MODEL) ? NELEM : 0);
      short4v pk;
#pragma unroll
      for (int r = 0; r < 4; ++r) pk[r] = (short)f2bf(acc[i][j][r] + b4[r]);
      *(short4v*)(C + (size_t)xrow * D_MODEL + (n0 & (D_MODEL - 1))) = pk;
    }
  }
}

// ---------------- qkv_v: v cols, normal order -> transposed 8B stores ----------------
__global__ __launch_bounds__(256)
void qkv_v(const unsigned short* __restrict__ xb,
           const unsigned short* __restrict__ wcat,    // +2048 rows = Wv
           const float* __restrict__ bcat,
           unsigned short* __restrict__ vT)            // [1024][8192]
{
  __shared__ unsigned short As[128 * 32];
  __shared__ unsigned short Bs[128 * 32];
  const int tid = threadIdx.x, lane = tid & 63, wave = tid >> 6;

  int gx = (int)gridDim.x, gy = (int)gridDim.y;
  int total = gx * gy;                                 // 512
  int flat  = (int)blockIdx.y * gx + (int)blockIdx.x;
  int w     = (flat & 7) * (total >> 3) + (flat >> 3);
  int bx = w % gx, by = w / gx;
  const int bm0 = by * 128;
  const int bn0 = bx * 128;                            // v col (local)
  const int wm = (wave >> 1) * 64, wn = (wave & 1) * 64;
  const unsigned short* Wg = wcat + (size_t)2048 * D_MODEL;

  floatx4 acc[4][4] = {};
  for (int k0 = 0; k0 < D_MODEL; k0 += 32) {
#pragma unroll
    for (int t = 0; t < 2; ++t) {
      int bu = wave * 64 + t * 256;
      int u  = bu + lane;
      const unsigned short* srcA = xb + (size_t)(bm0 + (u >> 2)) * D_MODEL + k0 + (u & 3) * 8;
      __builtin_amdgcn_global_load_lds((const __attribute__((address_space(1))) void*)srcA,
                                       (__attribute__((address_space(3))) void*)(As + bu * 8), 16, 0, 0);
      const unsigned short* srcB = Wg + (size_t)(bn0 + (u >> 2)) * D_MODEL + k0 + (u & 3) * 8;
      __builtin_amdgcn_global_load_lds((const __attribute__((address_space(1))) void*)srcB,
                                       (__attribute__((address_space(3))) void*)(Bs + bu * 8), 16, 0, 0);
    }
    __syncthreads();
    short8 af[4], bf[4];
#pragma unroll
    for (int i = 0; i < 4; ++i)
      af[i] = *(const short8*)(As + (wm + i * 16 + (lane & 15)) * 32 + (lane >> 4) * 8);
#pragma unroll
    for (int j = 0; j < 4; ++j)
      bf[j] = *(const short8*)(Bs + (wn + j * 16 + (lane & 15)) * 32 + (lane >> 4) * 8);
#pragma unroll
    for (int i = 0; i < 4; ++i)
#pragma unroll
      for (int j = 0; j < 4; ++j)
        acc[i][j] = __builtin_amdgcn_mfma_f32_16x16x32_bf16(af[i], bf[j], acc[i][j], 0, 0, 0);
    __syncthreads();
  }

#pragma unroll
  for (int i = 0; i < 4; ++i) {
#pragma unroll
    for (int j = 0; j < 4; ++j) {
      int e     = bn0 + wn + j * 16 + (lane & 15);       // v col
      int rbase = bm0 + wm + i * 16 + (lane >> 4) * 4;   // x row base
      float b = bcat[2048 + e];
      short4v pk;
#pragma unroll
      for (int r = 0; r < 4; ++r) pk[r] = (short)f2bf(acc[i][j][r] + b);
      *(short4v*)(vT + (size_t)e * (BATCH * SEQ_N) + rbase) = pk;
    }
  }
}

// ---------------- band logits: 64-row x 128-col tiles, window [g*64-64, g*64+192) ----------------
__global__ __launch_bounds__(256)
void band_logits(const unsigned short* __restrict__ Q,
                 const unsigned short* __restrict__ Kb,
                 float* __restrict__ Sband,              // [8192][256]
                 const float* __restrict__ K1d)
{
  __shared__ unsigned short As[64 * 32];
  __shared__ unsigned short Bs[128 * 32];
  const int tid = threadIdx.x, lane = tid & 63, wave = tid >> 6;
  const int bx = blockIdx.x;             // 0..1 (128-col half of 256 window)
  const int g  = blockIdx.y;             // 0..63 (64-row group)
  const int z  = blockIdx.z;
  const int bm0 = g * 64;
  const int bn0 = g * 64 - 64 + bx * 128;     // may be <0 or >=4096 partially
  const int wm = (wave >> 1) * 32, wn = (wave & 1) * 64;

  const unsigned short* Ag = Q  + (size_t)z * SEQ_N * D_MODEL;
  const unsigned short* Bg = Kb + (size_t)z * SEQ_N * D_MODEL;

  floatx4 acc[2][4] = {};
  for (int k0 = 0; k0 < D_MODEL; k0 += 32) {
    {
      int bu = wave * 64;
      int u  = bu + lane;                 // 0..255 : A tile [64][32]
      const unsigned short* srcA = Ag + (size_t)(bm0 + (u >> 2)) * D_MODEL + k0 + (u & 3) * 8;
      __builtin_amdgcn_global_load_lds((const __attribute__((address_space(1))) void*)srcA,
                                       (__attribute__((address_space(3))) void*)(As + bu * 8), 16, 0, 0);
    }
#pragma unroll
    for (int t = 0; t < 2; ++t) {
      int bu = wave * 64 + t * 256;
      int u  = bu + lane;                 // B tile [128][32], rows may be OOB (finite ws data)
      const unsigned short* srcB = Bg + (long)(bn0 + (u >> 2)) * D_MODEL + k0 + (u & 3) * 8;
      __builtin_amdgcn_global_load_lds((const __attribute__((address_space(1))) void*)srcB,
                                       (__attribute__((address_space(3))) void*)(Bs + bu * 8), 16, 0, 0);
    }
    __syncthreads();
    short8 af[2], bf[4];
#pragma unroll
    for (int i = 0; i < 2; ++i)
      af[i] = *(const short8*)(As + (wm + i * 16 + (lane & 15)) * 32 + (lane >> 4) * 8);
#pragma unroll
    for (int j = 0; j < 4; ++j)
      bf[j] = *(const short8*)(Bs + (wn + j * 16 + (lane & 15)) * 32 + (lane >> 4) * 8);
#pragma unroll
    for (int i = 0; i < 2; ++i)
#pragma unroll
      for (int j = 0; j < 4; ++j)
        acc[i][j] = __builtin_amdgcn_mfma_f32_16x16x32_bf16(af[i], bf[j], acc[i][j], 0, 0, 0);
    __syncthreads();
  }

  float* Cb = Sband + ((size_t)z * SEQ_N + bm0) * BAND + bx * 128;
#pragma unroll
  for (int i = 0; i < 2; ++i) {
#pragma unroll
    for (int j = 0; j < 4; ++j) {
      int cl  = wn + j * 16 + (lane & 15);
      int rl0 = wm + i * 16 + (lane >> 4) * 4;
#pragma unroll
      for (int r = 0; r < 4; ++r) {
        int col = bn0 + cl;
        int d = (bm0 + rl0 + r) - col; d = d < 0 ? -d : d;   // <= 191
        float v = ((unsigned)col < (unsigned)SEQ_N) ? acc[i][j][r] * 0.03125f * K1d[d] : 0.f;
        Cb[(size_t)(rl0 + r) * BAND + cl] = v;
      }
    }
  }
}

// ---------------- band softmax: full attn row + bf16 (P-c) band + c ----------------
__global__ __launch_bounds__(256)
void softmax_band(const float* __restrict__ Sband,
                  float* __restrict__ attn,
                  unsigned short* __restrict__ Pb,
                  float* __restrict__ c_arr)
{
  __shared__ float lds_e[4][BAND];
  const int lane = threadIdx.x & 63, wave = threadIdx.x >> 6;
  const int gi = blockIdx.x * 4 + wave;     // 0..8191
  const int ii = gi & (SEQ_N - 1);
  const int g  = ii >> 6;
  const int cbase = g * 64 - 64;
  const float* S = Sband + (size_t)gi * BAND;

  float sv[4];
  float m = 0.0f;                           // far logits are exactly 0
#pragma unroll
  for (int j = 0; j < 4; ++j) {
    int t = j * 64 + lane;
    int col = cbase + t;
    sv[j] = S[t];
    if ((unsigned)col < (unsigned)SEQ_N) m = fmaxf(m, sv[j]);
  }
#pragma unroll
  for (int o = 32; o; o >>= 1) m = fmaxf(m, __shfl_xor(m, o));

  float s = 0.f;
#pragma unroll
  for (int j = 0; j < 4; ++j) {
    int t = j * 64 + lane;
    int col = cbase + t;
    float e = ((unsigned)col < (unsigned)SEQ_N) ? __expf(sv[j] - m) : 0.f;
    sv[j] = e;
    s += e;
  }
#pragma unroll
  for (int o = 32; o; o >>= 1) s += __shfl_xor(s, o);

  int n_valid = BAND - ((g == 0) ? 64 : 0) - ((g == 63) ? 64 : 0);
  float efar  = __expf(-m);
  float denom = s + (float)(SEQ_N - n_valid) * efar;
  float inv   = 1.0f / denom;
  float c     = efar * inv;

  unsigned short* prow = Pb + (size_t)gi * BAND;
#pragma unroll
  for (int j = 0; j < 4; ++j) {
    int t = j * 64 + lane;
    float p = sv[j] * inv;
    lds_e[wave][t] = p;
    int col = cbase + t;
    prow[t] = ((unsigned)col < (unsigned)SEQ_N) ? f2bf(p - c) : (unsigned short)0;
  }
  if (lane == 0) c_arr[gi] = c;

  float* arow = attn + (size_t)gi * SEQ_N;
#pragma unroll
  for (int jj = 0; jj < 16; ++jj) {
    int col0 = jj * 256 + lane * 4;
    floatx4 o;
#pragma unroll
    for (int e = 0; e < 4; ++e) {
      int t = col0 + e - cbase;
      o[e] = ((unsigned)t < (unsigned)BAND) ? lds_e[wave][t] : c;
    }
    __builtin_nontemporal_store(o, (floatx4*)(arow + col0));
  }
}

// ---------------- colsumV[b][d] = sum_n vT[d][b*4096+n] ----------------
__global__ __launch_bounds__(256)
void colsumv_kernel(const unsigned short* __restrict__ vT, float* __restrict__ colsumV) {
  const int lane = threadIdx.x & 63, wave = threadIdx.x >> 6;
  const int idx = blockIdx.x * 4 + wave;     // 0..2047
  const int d = idx >> 1, b = idx & 1;
  const unsigned short* p = vT + (size_t)d * (BATCH * SEQ_N) + b * SEQ_N;
  float s = 0.f;
#pragma unroll
  for (int it = 0; it < 8; ++it) {
    short8 v = *(const short8*)(p + (size_t)(it * 512 + lane * 8));
#pragma unroll
    for (int e = 0; e < 8; ++e) s += bf2f((unsigned short)v[e]);
  }
#pragma unroll
  for (int o = 32; o; o >>= 1) s += __shfl_xor(s, o);
  if (lane == 0) colsumV[b * D_MODEL + d] = s;
}

// ---------------- band PV: out = (P-c) @ V_band + c * colsumV  (64-row tiles) ----------------
__global__ __launch_bounds__(256)
void band_pv(const unsigned short* __restrict__ Pb,   // [8192][256]
             const unsigned short* __restrict__ vT,   // [1024][8192]
             const float* __restrict__ c_arr,         // [8192]
             const float* __restrict__ colsumV,       // [2][1024]
             float* __restrict__ outp)                // [2][4096][1024]
{
  __shared__ unsigned short As[64 * 32];
  __shared__ unsigned short Bs[128 * 32];
  const int tid = threadIdx.x, lane = tid & 63, wave = tid >> 6;
  const int bx = blockIdx.x;     // 0..7  d-block (128 cols)
  const int g  = blockIdx.y;     // 0..63 64-row group
  const int z  = blockIdx.z;
  const int bm0 = g * 64;
  const int bn0 = bx * 128;
  const int wm = (wave >> 1) * 32, wn = (wave & 1) * 64;

  const unsigned short* Ag = Pb + ((size_t)z * SEQ_N + bm0) * BAND;
  // B row d, band col t -> vT[d][z*4096 + g*64 - 64 + t]; +-64 overrun lands in
  // adjacent ws buffers (finite bf16, always multiplied by P==0).
  const unsigned short* Bg = vT + (long)z * SEQ_N + (long)bm0 - 64;

  floatx4 acc[2][4] = {};
  for (int k0 = 0; k0 < BAND; k0 += 32) {
    {
      int bu = wave * 64;
      int u  = bu + lane;                 // A tile [64][32]
      const unsigned short* srcA = Ag + (size_t)(u >> 2) * BAND + k0 + (u & 3) * 8;
      __builtin_amdgcn_global_load_lds((const __attribute__((address_space(1))) void*)srcA,
                                       (__attribute__((address_space(3))) void*)(As + bu * 8), 16, 0, 0);
    }
#pragma unroll
    for (int t = 0; t < 2; ++t) {
      int bu = wave * 64 + t * 256;
      int u  = bu + lane;
      const unsigned short* srcB = Bg + (size_t)(bn0 + (u >> 2)) * (BATCH * SEQ_N) + k0 + (u & 3) * 8;
      __builtin_amdgcn_global_load_lds((const __attribute__((address_space(1))) void*)srcB,
                                       (__attribute__((address_space(3))) void*)(Bs + bu * 8), 16, 0, 0);
    }
    __syncthreads();
    short8 af[2], bf[4];
#pragma unroll
    for (int i = 0; i < 2; ++i)
      af[i] = *(const short8*)(As + (wm + i * 16 + (lane & 15)) * 32 + (lane >> 4) * 8);
#pragma unroll
    for (int j = 0; j < 4; ++j)
      bf[j] = *(const short8*)(Bs + (wn + j * 16 + (lane & 15)) * 32 + (lane >> 4) * 8);
#pragma unroll
    for (int i = 0; i < 2; ++i)
#pragma unroll
      for (int j = 0; j < 4; ++j)
        acc[i][j] = __builtin_amdgcn_mfma_f32_16x16x32_bf16(af[i], bf[j], acc[i][j], 0, 0, 0);
    __syncthreads();
  }

#pragma unroll
  for (int i = 0; i < 2; ++i) {
#pragma unroll
    for (int j = 0; j < 4; ++j) {
      int col   = bn0 + wn + j * 16 + (lane & 15);
      int rbase = bm0 + wm + i * 16 + (lane >> 4) * 4;
      float csv = colsumV[z * D_MODEL + col];
#pragma unroll
      for (int r = 0; r < 4; ++r) {
        int row = rbase + r;
        float o = acc[i][j][r] + c_arr[(size_t)z * SEQ_N + row] * csv;
        __builtin_nontemporal_store(o, outp + ((size_t)z * SEQ_N + row) * D_MODEL + col);
      }
    }
  }
}

// ---------------- fallback-path kernels (round-1 proven) ----------------
#define BM 128
#define BN 128
#define BK 32

template<int ASRC, int BSRC, int EPI>
__global__ __launch_bounds__(256)
void gemm_bt(const void* __restrict__ Ap_, int lda, long sA,
             const void* __restrict__ Bp_, int ldb, long sB,
             void* __restrict__ Cp_, int ldc, long sC,
             int K, const float* __restrict__ bias,
             const float* __restrict__ K1d)
{
  __shared__ unsigned short As[BM * BK];
  __shared__ unsigned short Bs[BN * BK];
  const int tid  = threadIdx.x;
  const int lane = tid & 63;
  const int wave = tid >> 6;

  int gx = (int)gridDim.x, gy = (int)gridDim.y;
  int total = gx * gy * (int)gridDim.z;
  int flat  = (int)blockIdx.z * gx * gy + (int)blockIdx.y * gx + (int)blockIdx.x;
  int w     = (flat & 7) * (total >> 3) + (flat >> 3);
  int bx = w % gx;
  int t_ = w / gx;
  int by = t_ % gy;
  int z  = t_ / gy;

  const int bm0  = by * BM;
  const int bn0  = bx * BN;
  const int wm   = (wave >> 1) * 64;
  const int wn   = (wave & 1) * 64;

  floatx4 acc[4][4] = {};

  const unsigned short* Agb = (const unsigned short*)Ap_ + (size_t)z * (size_t)sA;
  const float*          Agf = (const float*)Ap_          + (size_t)z * (size_t)sA;
  const unsigned short* Bgb = (const unsigned short*)Bp_ + (size_t)z * (size_t)sB;
  const float*          Bgf = (const float*)Bp_          + (size_t)z * (size_t)sB;

  for (int k0 = 0; k0 < K; k0 += BK) {
    if constexpr (ASRC == 0) {
#pragma unroll
      for (int t = 0; t < 2; ++t) {
        int bu = wave * 64 + t * 256;
        int u  = bu + lane;
        const unsigned short* src = Agb + (size_t)(bm0 + (u >> 2)) * lda + k0 + (u & 3) * 8;
        __builtin_amdgcn_global_load_lds((const __attribute__((address_space(1))) void*)src,
                                         (__attribute__((address_space(3))) void*)(As + bu * 8),
                                         16, 0, 0);
      }
    } else {
#pragma unroll
      for (int t = 0; t < 2; ++t) {
        int u = tid + t * 256;
        const float* src = Agf + (size_t)(bm0 + (u >> 2)) * lda + k0 + (u & 3) * 8;
        floatx4 x0 = *(const floatx4*)src;
        floatx4 x1 = *(const floatx4*)(src + 4);
        short8 pk;
        pk[0] = (short)f2bf(x0[0]); pk[1] = (short)f2bf(x0[1]);
        pk[2] = (short)f2bf(x0[2]); pk[3] = (short)f2bf(x0[3]);
        pk[4] = (short)f2bf(x1[0]); pk[5] = (short)f2bf(x1[1]);
        pk[6] = (short)f2bf(x1[2]); pk[7] = (short)f2bf(x1[3]);
        *(short8*)(As + u * 8) = pk;
      }
    }
    if constexpr (BSRC == 0) {
#pragma unroll
      for (int t = 0; t < 2; ++t) {
        int bu = wave * 64 + t * 256;
        int u  = bu + lane;
        const unsigned short* src = Bgb + (size_t)(bn0 + (u >> 2)) * ldb + k0 + (u & 3) * 8;
        __builtin_amdgcn_global_load_lds((const __attribute__((address_space(1))) void*)src,
                                         (__attribute__((address_space(3))) void*)(Bs + bu * 8),
                                         16, 0, 0);
      }
    } else {
#pragma unroll
      for (int t = 0; t < 2; ++t) {
        int u = tid + t * 256;
        const float* src = Bgf + (size_t)(bn0 + (u >> 2)) * ldb + k0 + (u & 3) * 8;
        floatx4 x0 = *(const floatx4*)src;
        floatx4 x1 = *(const floatx4*)(src + 4);
        short8 pk;
        pk[0] = (short)f2bf(x0[0]); pk[1] = (short)f2bf(x0[1]);
        pk[2] = (short)f2bf(x0[2]); pk[3] = (short)f2bf(x0[3]);
        pk[4] = (short)f2bf(x1[0]); pk[5] = (short)f2bf(x1[1]);
        pk[6] = (short)f2bf(x1[2]); pk[7] = (short)f2bf(x1[3]);
        *(short8*)(Bs + u * 8) = pk;
      }
    }
    __syncthreads();

    short8 af[4], bf[4];
#pragma unroll
    for (int i = 0; i < 4; ++i)
      af[i] = *(const short8*)(As + (wm + i * 16 + (lane & 15)) * BK + (lane >> 4) * 8);
#pragma unroll
    for (int j = 0; j < 4; ++j)
      bf[j] = *(const short8*)(Bs + (wn + j * 16 + (lane & 15)) * BK + (lane >> 4) * 8);
#pragma unroll
    for (int i = 0; i < 4; ++i)
#pragma unroll
      for (int j = 0; j < 4; ++j)
        acc[i][j] = __builtin_amdgcn_mfma_f32_16x16x32_bf16(af[i], bf[j], acc[i][j], 0, 0, 0);
    __syncthreads();
  }

  const int col0 = bn0 + wn;
  const int row0 = bm0 + wm;
#pragma unroll
  for (int i = 0; i < 4; ++i) {
#pragma unroll
    for (int j = 0; j < 4; ++j) {
      int col   = col0 + j * 16 + (lane & 15);
      int rbase = row0 + i * 16 + (lane >> 4) * 4;
      if constexpr (EPI == 0) {
        unsigned short* C = (unsigned short*)Cp_ + (size_t)z * (size_t)sC;
        float b = bias[col];
#pragma unroll
        for (int r = 0; r < 4; ++r)
          C[(size_t)(rbase + r) * ldc + col] = f2bf(acc[i][j][r] + b);
      } else if constexpr (EPI == 1) {
        unsigned short* C = (unsigned short*)Cp_ + (size_t)z * (size_t)sC;
#pragma unroll
        for (int r = 0; r < 4; ++r)
          C[(size_t)(rbase + r) * ldc + col] = f2bf(acc[i][j][r] + bias[rbase + r]);
      } else if constexpr (EPI == 2) {
        float* C = (float*)Cp_ + (size_t)z * (size_t)sC;
#pragma unroll
        for (int r = 0; r < 4; ++r) {
          int row = rbase + r;
          int d = row - col; d = d < 0 ? -d : d;
          C[(size_t)row * ldc + col] = acc[i][j][r] * 0.03125f * K1d[d];
        }
      } else {
        float* C = (float*)Cp_ + (size_t)z * (size_t)sC;
#pragma unroll
        for (int r = 0; r < 4; ++r)
          C[(size_t)(rbase + r) * ldc + col] = acc[i][j][r];
      }
    }
  }
}

__global__ __launch_bounds__(256)
void softmax_kernel(float* __restrict__ attn) {
  const int tid = threadIdx.x;
  float* p = attn + (size_t)blockIdx.x * SEQ_N;
  floatx4* p4 = (floatx4*)p;
  floatx4 x[4];
  float m = -3.402823466e+38f;
#pragma unroll
  for (int c = 0; c < 4; ++c) {
    x[c] = p4[tid + c * 256];
    m = fmaxf(m, fmaxf(fmaxf(x[c][0], x[c][1]), fmaxf(x[c][2], x[c][3])));
  }
#pragma unroll
  for (int o = 32; o; o >>= 1) m = fmaxf(m, __shfl_xor(m, o));
  __shared__ float redm[4], reds[4];
  if ((tid & 63) == 0) redm[tid >> 6] = m;
  __syncthreads();
  m = fmaxf(fmaxf(redm[0], redm[1]), fmaxf(redm[2], redm[3]));
  float s = 0.f;
#pragma unroll
  for (int c = 0; c < 4; ++c)
#pragma unroll
    for (int e = 0; e < 4; ++e) {
      float t = __expf(x[c][e] - m);
      x[c][e] = t;
      s += t;
    }
#pragma unroll
  for (int o = 32; o; o >>= 1) s += __shfl_xor(s, o);
  if ((tid & 63) == 0) reds[tid >> 6] = s;
  __syncthreads();
  s = reds[0] + reds[1] + reds[2] + reds[3];
  float inv = 1.0f / s;
#pragma unroll
  for (int c = 0; c < 4; ++c) {
    floatx4 y;
#pragma unroll
    for (int e = 0; e < 4; ++e) y[e] = x[c][e] * inv;
    p4[tid + c * 256] = y;
  }
}

extern "C" void kernel_launch(void* const* d_in, const int* in_sizes, int n_in,
                              void* d_out, int out_size, void* d_ws, size_t ws_size,
                              hipStream_t stream) {
  const float* x     = (const float*)d_in[0];
  const float* Wq    = (const float*)d_in[1];
  const float* bq    = (const float*)d_in[2];
  const float* Wk    = (const float*)d_in[3];
  const float* bk    = (const float*)d_in[4];
  const float* Wv    = (const float*)d_in[5];
  const float* bv    = (const float*)d_in[6];
  const float* alpha = (const float*)d_in[7];
  const float* lam   = (const float*)d_in[8];

  float* outp  = (float*)d_out;
  float* attnp = outp + (size_t)BATCH * SEQ_N * D_MODEL;
  float* Kp    = attnp + (size_t)BATCH * SEQ_N * SEQ_N;

  char* ws = (char*)d_ws;
  float* K1d = (float*)ws;                                 // 16 KB
  unsigned short* qb  = (unsigned short*)(ws + 16384);     // [8192][1024]
  unsigned short* kb  = qb + NELEM;                        // [8192][1024]
  unsigned short* vT  = kb + NELEM;                        // [1024][8192]
  unsigned short* xb  = vT + NELEM;                        // [8192][1024]
  unsigned short* wcat = xb + NELEM;                       // [3072][1024]
  float* Sband        = (float*)(wcat + (size_t)3 * D_MODEL * D_MODEL); // [8192][256]
  unsigned short* Pb  = (unsigned short*)(Sband + (size_t)BATCH * SEQ_N * BAND);
  float* c_arr        = (float*)(Pb + (size_t)BATCH * SEQ_N * BAND);   // [8192]
  float* colsumV      = c_arr + (size_t)BATCH * SEQ_N;                 // [2][1024]
  float* bcat         = colsumV + (size_t)BATCH * D_MODEL;             // [3072]

  size_t need = (size_t)((char*)(bcat + 3 * D_MODEL) - ws);
  const bool fast = ws_size >= need;

  if (fast) {
    fused_prep<<<5660, 256, 0, stream>>>(x, Wq, Wk, Wv, bq, bk, bv, alpha, lam,
                                         xb, wcat, bcat, K1d);
    writeK_kernel<<<(SEQ_N * SEQ_N / 4) / 256, 256, 0, stream>>>(Kp, K1d);

    qkv_qk<<<dim3(16, 64), 256, 0, stream>>>(xb, wcat, bcat, qb);
    qkv_v <<<dim3(8, 64), 256, 0, stream>>>(xb, wcat, bcat, vT);

    colsumv_kernel<<<BATCH * D_MODEL / 4, 256, 0, stream>>>(vT, colsumV);
    band_logits<<<dim3(2, SEQ_N / 64, BATCH), 256, 0, stream>>>(qb, kb, Sband, K1d);
    softmax_band<<<BATCH * SEQ_N / 4, 256, 0, stream>>>(Sband, attnp, Pb, c_arr);
    band_pv<<<dim3(D_MODEL / 128, SEQ_N / 64, BATCH), 256, 0, stream>>>(
        Pb, vT, c_arr, colsumV, outp);
  } else {
    // fallback: round-1 proven path
    k1d_kernel<<<16, 256, 0, stream>>>(K1d, alpha, lam);
    writeK_kernel<<<(SEQ_N * SEQ_N / 4) / 256, 256, 0, stream>>>(Kp, K1d);
    gemm_bt<1, 1, 0><<<dim3(D_MODEL / BN, BATCH * SEQ_N / BM, 1), 256, 0, stream>>>(
        x, D_MODEL, 0, Wq, D_MODEL, 0, qb, D_MODEL, 0, D_MODEL, bq, nullptr);
    gemm_bt<1, 1, 0><<<dim3(D_MODEL / BN, BATCH * SEQ_N / BM, 1), 256, 0, stream>>>(
        x, D_MODEL, 0, Wk, D_MODEL, 0, kb, D_MODEL, 0, D_MODEL, bk, nullptr);
    gemm_bt<1, 1, 1><<<dim3(BATCH * SEQ_N / BN, D_MODEL / BM, 1), 256, 0, stream>>>(
        Wv, D_MODEL, 0, x, D_MODEL, 0, vT, BATCH * SEQ_N, 0, D_MODEL, bv, nullptr);
    gemm_bt<0, 0, 2><<<dim3(SEQ_N / BN, SEQ_N / BM, BATCH), 256, 0, stream>>>(
        qb, D_MODEL, (long)SEQ_N * D_MODEL, kb, D_MODEL, (long)SEQ_N * D_MODEL,
        attnp, SEQ_N, (long)SEQ_N * SEQ_N, D_MODEL, nullptr, K1d);
    softmax_kernel<<<BATCH * SEQ_N, 256, 0, stream>>>(attnp);
    gemm_bt<1, 0, 3><<<dim3(D_MODEL / BN, SEQ_N / BM, BATCH), 256, 0, stream>>>(
        attnp, SEQ_N, (long)SEQ_N * SEQ_N, vT, BATCH * SEQ_N, (long)SEQ_N,
        outp, D_MODEL, (long)SEQ_N * D_MODEL, SEQ_N, nullptr, nullptr);
  }
}